// Round 5
// baseline (1233.333 us; speedup 1.0000x reference)
//
#include <hip/hip_runtime.h>
#include <math.h>

// ---------------- problem constants ----------------
#define SEQ_LEN 8
#define IN_DIM 2048
#define OUT_DIM 1152
#define NTUP 56
#define NSUP 25
#define NQ 200
#define WAY 5
#define SFRAMES 200
#define NFRAMES 1800
#define SROWS 1400
#define QROWS 11200
#define AT_STRIDE 1440   // bf16 scores/G1 row stride: 5 classes * 288
#define KC 288           // per-class padded K (280 valid + 8 zeros)
#define ALD 296          // attn LDS row stride (shorts)

typedef __attribute__((ext_vector_type(8))) short short8;
typedef __attribute__((ext_vector_type(4))) float f32x4;

__device__ __constant__ int TUP[NTUP][3] = {
{0,1,2},{0,1,3},{0,1,4},{0,1,5},{0,1,6},{0,1,7},
{0,2,3},{0,2,4},{0,2,5},{0,2,6},{0,2,7},
{0,3,4},{0,3,5},{0,3,6},{0,3,7},
{0,4,5},{0,4,6},{0,4,7},
{0,5,6},{0,5,7},
{0,6,7},
{1,2,3},{1,2,4},{1,2,5},{1,2,6},{1,2,7},
{1,3,4},{1,3,5},{1,3,6},{1,3,7},
{1,4,5},{1,4,6},{1,4,7},
{1,5,6},{1,5,7},
{1,6,7},
{2,3,4},{2,3,5},{2,3,6},{2,3,7},
{2,4,5},{2,4,6},{2,4,7},
{2,5,6},{2,5,7},
{2,6,7},
{3,4,5},{3,4,6},{3,4,7},
{3,5,6},{3,5,7},
{3,6,7},
{4,5,6},{4,5,7},
{4,6,7},
{5,6,7}};

// ---------------- bf16 helpers ----------------
__device__ __forceinline__ unsigned short f2bf(float x) {
  union { float f; unsigned int u; } v; v.f = x;
  unsigned int r = v.u + 0x7fffu + ((v.u >> 16) & 1u);
  return (unsigned short)(r >> 16);
}
__device__ __forceinline__ float bf2f(unsigned short s) {
  union { float f; unsigned int u; } v; v.u = ((unsigned int)s) << 16;
  return v.f;
}

// async 16B global -> LDS (dest = wave-uniform base + lane*16; tid-contiguous ok)
__device__ __forceinline__ void gll16(const void* g, void* l) {
  __builtin_amdgcn_global_load_lds(
      (const __attribute__((address_space(1))) unsigned int*)g,
      (__attribute__((address_space(3))) unsigned int*)l, 16, 0, 0);
}

// counted vmcnt wait (T4)
#define VMCNT(N) asm volatile("s_waitcnt vmcnt(" #N ")" ::: "memory")

// raw workgroup barrier WITHOUT the compiler's vmcnt(0) drain
__device__ __forceinline__ void pbar() {
  asm volatile("" ::: "memory");
  __builtin_amdgcn_s_barrier();
  asm volatile("" ::: "memory");
}

// ---------------- workspace byte offsets ----------------
#define APB_OFF   0UL                     // bf16 [1800][2048]
#define WT_OFF    7372800UL               // bf16 [6912][2048]
#define PB_OFF    35684352UL              // bf16 [1800][6912]
#define QKB_OFF   60567552UL              // bf16 [11200][1152]
#define SKB_OFF   86372352UL              // bf16 [1400][1152] class-sorted
#define QVB_OFF   89597952UL              // bf16 [11200][1152]
#define SVB_OFF   115402752UL             // bf16 [1400][1152] class-sorted
#define G2_OFF    118628352UL             // bf16 [5][288][288] Gram
#define SCB_OFF   119457792UL             // bf16 [11200][1440] class-padded
#define G1B_OFF   151713792UL             // bf16 [11200][1440] class-padded
#define QNORM_OFF 183969792UL             // f32  [11200]
#define RANK_OFF  184014592UL             // i32  [25]

// ---------------- k_pre: fused (X+PE)->bf16, weight transpose, rank, out-zero ----------------
__global__ __launch_bounds__(256) void k_pre(const float* __restrict__ S,
                                             const float* __restrict__ Q,
                                             const float* __restrict__ Wk,
                                             const float* __restrict__ Wv,
                                             const int* __restrict__ labels,
                                             unsigned short* __restrict__ APb,
                                             unsigned short* __restrict__ WT,
                                             int* __restrict__ rank,
                                             float* __restrict__ outz) {
  __shared__ float t[32][33];
  int b = blockIdx.x, tid = threadIdx.x;
  if (b < NFRAMES) {
    int frame = b;
    int e8 = tid * 8;
    int pos = frame & 7;
    const float c0 = -logf(10000.0f) / (float)IN_DIM;
    float pe[8];
#pragma unroll
    for (int p = 0; p < 4; ++p) {
      float dt = expf((float)(e8 + 2 * p) * c0);
      float arg = (float)pos * dt;
      pe[2 * p] = sinf(arg) * 0.1f;
      pe[2 * p + 1] = cosf(arg) * 0.1f;
    }
    const float* src = (frame < SFRAMES) ? (S + (size_t)frame * IN_DIM + e8)
                                         : (Q + (size_t)(frame - SFRAMES) * IN_DIM + e8);
    float4 x0 = ((const float4*)src)[0], x1 = ((const float4*)src)[1];
    short8 o;
    o[0] = (short)f2bf(x0.x + pe[0]); o[1] = (short)f2bf(x0.y + pe[1]);
    o[2] = (short)f2bf(x0.z + pe[2]); o[3] = (short)f2bf(x0.w + pe[3]);
    o[4] = (short)f2bf(x1.x + pe[4]); o[5] = (short)f2bf(x1.y + pe[5]);
    o[6] = (short)f2bf(x1.z + pe[6]); o[7] = (short)f2bf(x1.w + pe[7]);
    *(short8*)(APb + (size_t)frame * IN_DIM + e8) = o;
  } else if (b < NFRAMES + 13824) {
    int z = b - NFRAMES;                  // 64 k-tiles x 36 d-tiles x 6 (w,j)
    int bz = z / (64 * 36); int rem = z % (64 * 36);
    int by = rem / 64, bx = rem % 64;
    int w = bz / 3, j = bz % 3;
    const float* W = w ? Wv : Wk;
    int k0 = bx * 32, d0 = by * 32;
    int tx = tid & 31, ty = tid >> 5;
#pragma unroll
    for (int i = 0; i < 4; ++i) {
      int k = k0 + ty + i * 8;
      t[ty + i * 8][tx] = W[(size_t)(j * IN_DIM + k) * OUT_DIM + d0 + tx];
    }
    __syncthreads();
    int colbase = w * 3456 + j * 1152 + d0;
#pragma unroll
    for (int i = 0; i < 4; ++i) {
      int d = ty + i * 8;
      WT[(size_t)(colbase + d) * IN_DIM + k0 + tx] = f2bf(t[tx][d]);
    }
  } else {
    for (int i = tid; i < NQ * WAY; i += 256) outz[i] = 0.f;
    if (tid == 0) {
      for (int s = 0; s < NSUP; ++s) {
        int r = 0;
        for (int s2 = 0; s2 < NSUP; ++s2)
          r += (labels[s2] < labels[s]) || (labels[s2] == labels[s] && s2 < s);
        rank[s] = r;
      }
    }
  }
}

// ---------------- MFMA GEMM core: BM=256 x BN=128, BK=32, 256 thr / 4 waves ----------------
// Round-4 diagnosis: the kernel is LDS-THROUGHPUT-bound (72 KB LDS traffic per
// block-iter ~= 93% of measured wall; all schedule variants neutral). Fix: B no
// longer goes through LDS at all. B-fragments are loaded straight from global
// (L2-resident panels) into registers with a depth-1 ping-pong (bfA/bfB); per
// wave-load the 64 lanes cover 16 rows x 64 contiguous bytes -> fine coalescing.
// LDS now carries A only: 3 x 16 KB rotating buffers, depth-2 gll16 prefetch,
// chunk-XOR layout (0 conflicts, round-2 proven). LDS traffic/iter: 72 -> 48 KB.
// vmcnt: per sub-iter issue {4 B-loads, 4 A-gll16}; end-of-iter VMCNT(8) retires
// exactly A(t+1) while B(t+1)+A(t+2) stay in flight across the barrier; the
// compiler's own precise waits cover bf register uses. 48 KB LDS + <=170 VGPR
// allows 3 blocks/CU (__launch_bounds__(256,3)).
__device__ __forceinline__ void mfma_core256(const short* __restrict__ A, int lda, int maxA,
                                             const short* __restrict__ B, int ldb, int maxB,
                                             int K, short* lds, f32x4 (&acc)[8][4]) {
  int tid = threadIdx.x;
  int lane = tid & 63, wave = tid >> 6;
  int wm = wave >> 1, wn = wave & 1;
  int col = lane & 15, quad = lane >> 4;
  int kq8 = (quad ^ ((col >> 1) & 3)) * 8;     // read-side swizzled k-chunk (shorts)

  // A staging: 1024 slots (256 rows x 4 chunks), 4 gll16/thread
  int rt_ = tid >> 2;                          // slot row base 0..63
  int qo = ((tid & 3) ^ ((tid >> 3) & 3)) * 8; // inverse-swizzled source chunk
  const short* a0p = A + (size_t)min(rt_,       maxA) * lda + qo;
  const short* a1p = A + (size_t)min(rt_ + 64,  maxA) * lda + qo;
  const short* a2p = A + (size_t)min(rt_ + 128, maxA) * lda + qo;
  const short* a3p = A + (size_t)min(rt_ + 192, maxA) * lda + qo;
  // B per-lane direct global pointers (no LDS)
  const short* bp0 = B + (size_t)min(wn * 64 + col,      maxB) * ldb + quad * 8;
  const short* bp1 = B + (size_t)min(wn * 64 + 16 + col, maxB) * ldb + quad * 8;
  const short* bp2 = B + (size_t)min(wn * 64 + 32 + col, maxB) * ldb + quad * 8;
  const short* bp3 = B + (size_t)min(wn * 64 + 48 + col, maxB) * ldb + quad * 8;
  const int nt = K >> 5;                       // even at all call sites (36 or 64)

#define STAGEA(t, cb)                                \
  do {                                               \
    short* buf_ = lds + (cb);                        \
    int k0_ = (t) << 5;                              \
    gll16(a0p + k0_, buf_ + (size_t)tid * 8);        \
    gll16(a1p + k0_, buf_ + (size_t)(tid + 256) * 8);\
    gll16(a2p + k0_, buf_ + (size_t)(tid + 512) * 8);\
    gll16(a3p + k0_, buf_ + (size_t)(tid + 768) * 8);\
  } while (0)
#define LOADB(dst, t)                                \
  do {                                               \
    int k0_ = (t) << 5;                              \
    dst[0] = *(const short8*)(bp0 + k0_);            \
    dst[1] = *(const short8*)(bp1 + k0_);            \
    dst[2] = *(const short8*)(bp2 + k0_);            \
    dst[3] = *(const short8*)(bp3 + k0_);            \
  } while (0)
#define MFMA16(BF)                                                                     \
  do {                                                                                 \
    short8 af[8];                                                                      \
    _Pragma("unroll")                                                                  \
    for (int i = 0; i < 8; ++i)                                                        \
      af[i] = *(const short8*)(As + (wm * 128 + i * 16 + col) * 32 + kq8);             \
    __builtin_amdgcn_s_setprio(1);                                                     \
    _Pragma("unroll")                                                                  \
    for (int i = 0; i < 8; ++i)                                                        \
      _Pragma("unroll")                                                                \
      for (int j = 0; j < 4; ++j)                                                      \
        acc[i][j] = __builtin_amdgcn_mfma_f32_16x16x32_bf16(af[i], BF[j], acc[i][j],   \
                                                            0, 0, 0);                  \
    __builtin_amdgcn_s_setprio(0);                                                     \
  } while (0)

  short8 bfA[4], bfB[4];
  // prologue: B(0) regs, A(0) + A(1) staged; confirm B(0)+A(0), A(1) rides on
  LOADB(bfA, 0);
  STAGEA(0, 0);
  STAGEA(1, 8192);
  VMCNT(4);
  pbar();
  int c0 = 0, c1 = 8192, c2 = 16384;           // rotating A-buffer offsets (shorts)
  for (int t = 0; t < nt; t += 2) {
    {   // ---- even sub-iter: compute bfA from buf c0; load bfB; stage A(t+2) ----
      LOADB(bfB, t + 1);                       // t+1 < nt always (nt even)
      if (t + 2 < nt) STAGEA(t + 2, c2);
      const short* As = lds + c0;
      MFMA16(bfA);
      if (t + 2 < nt) { VMCNT(8); }            // A(t+1) landed; B(t+1)+A(t+2) in flight
      else            { VMCNT(4); }            // A(t+1) landed; B(t+1) in flight
      pbar();
      int tmp = c0; c0 = c1; c1 = c2; c2 = tmp;
    }
    {   // ---- odd sub-iter u = t+1: compute bfB from buf c0; load bfA; stage A(u+2) ----
      int u = t + 1;
      if (u + 1 < nt) LOADB(bfA, u + 1);
      if (u + 2 < nt) STAGEA(u + 2, c2);
      const short* As = lds + c0;
      MFMA16(bfB);
      if (u + 2 < nt)      { VMCNT(8); pbar(); }
      else if (u + 1 < nt) { VMCNT(4); pbar(); }
      // last sub-iter: nothing issued, no LDS use after -> no wait/barrier
      int tmp = c0; c0 = c1; c1 = c2; c2 = tmp;
    }
  }
#undef STAGEA
#undef LOADB
#undef MFMA16
}

// ---------------- GEMM1: Pb[1800][6912] = APb @ WT^T (256x128 tiles) ----------------
__global__ __launch_bounds__(256, 3) void k_gemm1(const unsigned short* __restrict__ APb,
                                                  const unsigned short* __restrict__ WT,
                                                  unsigned short* __restrict__ Pb) {
  __shared__ short lds[24576];           // 3 x 16KB A-pipeline buffers
  int o = blockIdx.x;                    // 432 blocks; XCD swizzle (432 % 8 == 0)
  int L = (o & 7) * 54 + (o >> 3);
  int rt = L / 54, ct = L % 54;
  int row0 = rt << 8, col0 = ct << 7;
  f32x4 acc[8][4];
#pragma unroll
  for (int i = 0; i < 8; ++i)
#pragma unroll
    for (int j = 0; j < 4; ++j) acc[i][j] = (f32x4)(0.f);
  mfma_core256((const short*)APb + (size_t)row0 * IN_DIM, IN_DIM, min(255, NFRAMES - 1 - row0),
               (const short*)WT + (size_t)col0 * IN_DIM, IN_DIM, 127,
               IN_DIM, lds, acc);
  int lane = threadIdx.x & 63, wave = threadIdx.x >> 6;
  int wm = wave >> 1, wn = wave & 1, col = lane & 15, quad = lane >> 4;
#pragma unroll
  for (int i = 0; i < 8; ++i)
#pragma unroll
    for (int r = 0; r < 4; ++r) {
      int gr = row0 + wm * 128 + i * 16 + quad * 4 + r;
      if (gr >= NFRAMES) continue;
#pragma unroll
      for (int j = 0; j < 4; ++j)
        Pb[(size_t)gr * 6912 + col0 + wn * 64 + j * 16 + col] = f2bf(acc[i][j][r]);
    }
}

// ---------------- combine (clip-LDS): one block per (clip, k/v) ----------------
__global__ __launch_bounds__(256) void k_combine(const unsigned short* __restrict__ Pb,
                                                 const float* __restrict__ bk,
                                                 const float* __restrict__ bv,
                                                 const float* __restrict__ g,
                                                 const float* __restrict__ bb,
                                                 const int* __restrict__ rank,
                                                 unsigned short* __restrict__ SKb,
                                                 unsigned short* __restrict__ QKb,
                                                 unsigned short* __restrict__ SVb,
                                                 unsigned short* __restrict__ QVb,
                                                 float* __restrict__ qnorm) {
  __shared__ short L[8 * 3456];
  int n = blockIdx.x, w = blockIdx.y;
  int tid = threadIdx.x;
  bool sup = n < NSUP;
  int fbase = sup ? n * SEQ_LEN : SFRAMES + (n - NSUP) * SEQ_LEN;
  for (int i = 0; i < 14; ++i) {
    int idx = tid + 256 * i;          // vec8 index < 3456
    if (idx < 3456) {
      int fr = idx / 432, off = (idx - fr * 432) * 8;
      *(short8*)(L + fr * 3456 + off) =
          *(const short8*)(Pb + (size_t)(fbase + fr) * 6912 + w * 3456 + off);
    }
  }
  __syncthreads();
  int wave = tid >> 6, lane = tid & 63;
  const float* bias = w ? bv : bk;
  float2 bi[9], gg[9], bbv[9];
#pragma unroll
  for (int i = 0; i < 9; ++i) {
    int p = lane + 64 * i;
    bi[i] = *(const float2*)(bias + 2 * p);
    if (w == 0) {
      gg[i] = *(const float2*)(g + 2 * p);
      bbv[i] = *(const float2*)(bb + 2 * p);
    }
  }
  int obase = sup ? rank[n] * NTUP : (n - NSUP) * NTUP;
  const unsigned int* Lu = (const unsigned int*)L;
  for (int t = wave; t < NTUP; t += 4) {
    int b0 = (TUP[t][0] * 3456) >> 1;
    int b1 = (TUP[t][1] * 3456 + 1152) >> 1;
    int b2 = (TUP[t][2] * 3456 + 2304) >> 1;
    float va[18];
    float sum = 0.f, sq = 0.f;
#pragma unroll
    for (int i = 0; i < 9; ++i) {
      int p = lane + 64 * i;
      unsigned int u0 = Lu[b0 + p], u1 = Lu[b1 + p], u2 = Lu[b2 + p];
      float a = bf2f((unsigned short)u0) + bf2f((unsigned short)u1) +
                bf2f((unsigned short)u2) + bi[i].x;
      float b = bf2f((unsigned short)(u0 >> 16)) + bf2f((unsigned short)(u1 >> 16)) +
                bf2f((unsigned short)(u2 >> 16)) + bi[i].y;
      va[2 * i] = a; va[2 * i + 1] = b;
      sum += a + b;
      sq += a * a + b * b;
    }
#pragma unroll
    for (int o = 32; o; o >>= 1) {
      sum += __shfl_xor(sum, o);
      sq += __shfl_xor(sq, o);
    }
    int orow = obase + t;
    if (w == 0) {
      float mean = sum * (1.f / OUT_DIM);
      float var = sq * (1.f / OUT_DIM) - mean * mean;
      float inv = rsqrtf(var + 1e-5f);
      unsigned short* outp = (sup ? SKb : QKb) + (size_t)orow * OUT_DIM;
#pragma unroll
      for (int i = 0; i < 9; ++i) {
        int p = lane + 64 * i;
        unsigned int lo = f2bf((va[2 * i] - mean) * inv * gg[i].x + bbv[i].x);
        unsigned int hi = f2bf((va[2 * i + 1] - mean) * inv * gg[i].y + bbv[i].y);
        *(unsigned int*)(outp + 2 * p) = lo | (hi << 16);
      }
    } else {
      unsigned short* outp = (sup ? SVb : QVb) + (size_t)orow * OUT_DIM;
#pragma unroll
      for (int i = 0; i < 9; ++i) {
        int p = lane + 64 * i;
        unsigned int lo = f2bf(va[2 * i]);
        unsigned int hi = f2bf(va[2 * i + 1]);
        *(unsigned int*)(outp + 2 * p) = lo | (hi << 16);
      }
      if (!sup && lane == 0) qnorm[orow] = sq;
    }
  }
}

// ---------------- merged: scores / G1 + Gram G2 (256x128 tiles) ----------------
// 998 blocks: 968 scores/G1 (44 rt x 11 ct x 2) + 30 G2 (5 classes x 2 rt x 3 ct)
__global__ __launch_bounds__(256, 3) void k_rowgemm(const unsigned short* __restrict__ QKb,
                                                    const unsigned short* __restrict__ SKb,
                                                    const unsigned short* __restrict__ QVb,
                                                    const unsigned short* __restrict__ SVb,
                                                    unsigned short* __restrict__ SCb,
                                                    unsigned short* __restrict__ G1b,
                                                    unsigned short* __restrict__ G2) {
  __shared__ short lds[24576];           // 3 x 16KB A-pipeline buffers
  int o = blockIdx.x;                    // bijective XCD swizzle for nwg=998 (q=124,r=6)
  int xcd = o & 7, idx = o >> 3;
  int L = (xcd < 6 ? xcd * 125 : 750 + (xcd - 6) * 124) + idx;
  f32x4 acc[8][4];
#pragma unroll
  for (int i = 0; i < 8; ++i)
#pragma unroll
    for (int j = 0; j < 4; ++j) acc[i][j] = (f32x4)(0.f);
  int lane = threadIdx.x & 63, wave = threadIdx.x >> 6;
  int wm = wave >> 1, wn = wave & 1, col = lane & 15, quad = lane >> 4;

  if (L < 968) {
    int g1 = L >= 484; int l = g1 ? L - 484 : L;
    int rt = l / 11, ct = l % 11;
    int row0 = rt << 8, col0 = ct << 7;
    const unsigned short* Am = g1 ? QVb : QKb;
    const unsigned short* Bm = g1 ? SVb : SKb;
    mfma_core256((const short*)Am + (size_t)row0 * OUT_DIM, OUT_DIM, min(255, QROWS - 1 - row0),
                 (const short*)Bm + (size_t)col0 * OUT_DIM, OUT_DIM, min(127, SROWS - 1 - col0),
                 OUT_DIM, lds, acc);
    unsigned short* outp = g1 ? G1b : SCb;
    const float scl = g1 ? 1.0f : 0.029462782549439483f;  // 1/sqrt(1152)
#pragma unroll
    for (int i = 0; i < 8; ++i)
#pragma unroll
      for (int r = 0; r < 4; ++r) {
        int gr = row0 + wm * 128 + i * 16 + quad * 4 + r;
        if (gr >= QROWS) continue;
#pragma unroll
        for (int j = 0; j < 4; ++j) {
          int gc = col0 + wn * 64 + j * 16 + col;
          if (gc < SROWS) {
            int c = gc / 280;
            outp[(size_t)gr * AT_STRIDE + gc + c * 8] = f2bf(acc[i][j][r] * scl);
          }
        }
      }
  } else {
    int l = L - 968;                  // 0..29: G2[c] = SV_c @ SV_c^T
    int c = l / 6, rem = l % 6;
    int rt = rem / 3, ct = rem % 3;
    int i0 = rt << 8, j0 = ct << 7;
    const short* base = (const short*)SVb + (size_t)c * 280 * OUT_DIM;
    mfma_core256(base + (size_t)i0 * OUT_DIM, OUT_DIM, 279 - i0,
                 base + (size_t)j0 * OUT_DIM, OUT_DIM, min(127, 279 - j0),
                 OUT_DIM, lds, acc);
    unsigned short* g2c = G2 + (size_t)c * KC * KC;
#pragma unroll
    for (int i = 0; i < 8; ++i)
#pragma unroll
      for (int r = 0; r < 4; ++r) {
        int gi = i0 + wm * 128 + i * 16 + quad * 4 + r;
        if (gi >= KC) continue;
#pragma unroll
        for (int j = 0; j < 4; ++j) {
          int gj = j0 + wn * 64 + j * 16 + col;
          if (gj < KC) g2c[(size_t)gi * KC + gj] = f2bf(acc[i][j][r]);
        }
      }
  }
}

// ---------------- k_attn: fused softmax + T2 + T3 (= e^T G2 e / S^2) + out atomics ----------------
__global__ __launch_bounds__(256) void k_attn(const unsigned short* __restrict__ SCb,
                                              const unsigned short* __restrict__ G1b,
                                              const unsigned short* __restrict__ G2,
                                              const float* __restrict__ qnorm,
                                              float* __restrict__ out) {
  __shared__ short attn[64 * ALD];     // 37,888 B
  __shared__ short Bs[64 * KC];        // 36,864 B
  __shared__ float T2n[64];
  __shared__ float Sarr[64];
  __shared__ float rowsum[64];
  __shared__ float val[64];
  int r0 = blockIdx.x * 64, c = blockIdx.y;
  int tid = threadIdx.x;

  // ---- phase 1: softmax numerators e = exp(s - M) -> LDS; S and T2 numerator ----
  int lr = tid >> 2, h = tid & 3;
  const unsigned short* ps = SCb + (size_t)(r0 + lr) * AT_STRIDE + c * KC;
  const unsigned short* pg = G1b + (size_t)(r0 + lr) * AT_STRIDE + c * KC;
  short8 sv[9];
  float mx = -INFINITY;
#pragma unroll
  for (int i = 0; i < 9; ++i) {
    int v = h * 9 + i;
    if (v < 35) {
      sv[i] = *(const short8*)(ps + v * 8);
#pragma unroll
      for (int j = 0; j < 8; ++j) mx = fmaxf(mx, bf2f((unsigned short)sv[i][j]));
    }
  }
  mx = fmaxf(mx, __shfl_xor(mx, 1));
  mx = fmaxf(mx, __shfl_xor(mx, 2));
  float sum = 0.f, t2 = 0.f;
#pragma unroll
  for (int i = 0; i < 9; ++i) {
    int v = h * 9 + i;
    if (v < 35) {
      short8 gv8 = *(const short8*)(pg + v * 8);
      short8 e8;
#pragma unroll
      for (int j = 0; j < 8; ++j) {
        float e = __expf(bf2f((unsigned short)sv[i][j]) - mx);
        sum += e;
        t2 += e * bf2f((unsigned short)gv8[j]);
        e8[j] = (short)f2bf(e);
      }
      *(short8*)(attn + lr * ALD + v * 8) = e8;
    } else {
      *(short8*)(attn + lr * ALD + v * 8) = (short8)0;   // zero class pad (v == 35)
    }
  }
  sum += __shfl_xor(sum, 1); sum += __shfl_xor(sum, 2);
  t2 += __shfl_xor(t2, 1); t2 += __shfl_xor(t2, 2);
  if (h == 0) { Sarr[lr] = sum; T2n[lr] = t2; }
  if (tid < 64) rowsum[tid] = 0.f;
  __syncthreads();

  // ---- phase 2: B2 = e @ G2 per 64-col slab; B staged full-K once per slab ----
  int lane = tid & 63, wave = tid >> 6;
  int col = lane & 15, quad = lane >> 4;
  const short* G2c = (const short*)G2 + (size_t)c * KC * KC;
  float part[4][4] = {};
  for (int j0 = 0; j0 < KC; j0 += 64) {
    int ncols = min(64, KC - j0);            // 64,64,64,64,32
    int chunks = ncols * 36;                 // 16-B chunks: 2304 or 1152
    for (int base = 0; base < chunks; base += 256) {
      int idx = base + tid;
      if (idx < chunks) {
        int n = idx / 36, kk = idx - n * 36;
        gll16(G2c + (size_t)(j0 + n) * KC + kk * 8, Bs + idx * 8);
      }
    }
    __syncthreads();
    if (wave * 16 < ncols) {
      f32x4 acc[4];
#pragma unroll
      for (int i = 0; i < 4; ++i) acc[i] = (f32x4)(0.f);
      for (int kq = 0; kq < 9; ++kq) {
        short8 bf = *(const short8*)(Bs + (wave * 16 + col) * KC + kq * 32 + quad * 8);
#pragma unroll
        for (int i = 0; i < 4; ++i) {
          short8 af = *(const short8*)(attn + (i * 16 + col) * ALD + kq * 32 + quad * 8);
          acc[i] = __builtin_amdgcn_mfma_f32_16x16x32_bf16(af, bf, acc[i], 0, 0, 0);
        }
      }
      int gcol = j0 + wave * 16 + col;
#pragma unroll
      for (int i = 0; i < 4; ++i)
#pragma unroll
        for (int r = 0; r < 4; ++r)
          part[i][r] += bf2f((unsigned short)attn[(i * 16 + quad * 4 + r) * ALD + gcol]) *
                        acc[i][r];
    }
    __syncthreads();
  }
  // reduce rowdot across the wave's 16 cols, then across waves via LDS atomics
#pragma unroll
  for (int i = 0; i < 4; ++i)
#pragma unroll
    for (int r = 0; r < 4; ++r) {
      float s = part[i][r];
      s += __shfl_xor(s, 1); s += __shfl_xor(s, 2);
      s += __shfl_xor(s, 4); s += __shfl_xor(s, 8);
      if (col == 0) atomicAdd(&rowsum[i * 16 + quad * 4 + r], s);
    }
  __syncthreads();

  // ---- phase 3: per-row distance, per-query reduce, one atomic per (q, c) ----
  if (tid < 64) {
    float S = Sarr[tid], invS = 1.f / S;
    val[tid] = qnorm[r0 + tid] - 2.f * T2n[tid] * invS + rowsum[tid] * invS * invS;
  }
  __syncthreads();
  if (tid < 3) {
    int q = r0 / NTUP + tid;
    int lo = max(q * NTUP, r0), hi = min(q * NTUP + NTUP, r0 + 64);
    if (lo < hi && q < NQ) {
      float s = 0.f;
      for (int r = lo; r < hi; ++r) s += val[r - r0];
      atomicAdd(&out[q * WAY + c], -s * (1.f / NTUP));
    }
  }
}

// ---------------- launch ----------------
extern "C" void kernel_launch(void* const* d_in, const int* in_sizes, int n_in,
                              void* d_out, int out_size, void* d_ws, size_t ws_size,
                              hipStream_t stream) {
  const float* support = (const float*)d_in[0];
  const int* labels = (const int*)d_in[1];
  const float* queries = (const float*)d_in[2];
  const float* Wk = (const float*)d_in[3];
  const float* bk = (const float*)d_in[4];
  const float* Wv = (const float*)d_in[5];
  const float* bv = (const float*)d_in[6];
  const float* ln_g = (const float*)d_in[7];
  const float* ln_b = (const float*)d_in[8];
  float* out = (float*)d_out;
  char* w8 = (char*)d_ws;

  unsigned short* APb = (unsigned short*)(w8 + APB_OFF);
  unsigned short* WT = (unsigned short*)(w8 + WT_OFF);
  unsigned short* Pb = (unsigned short*)(w8 + PB_OFF);
  unsigned short* QKb = (unsigned short*)(w8 + QKB_OFF);
  unsigned short* SKb = (unsigned short*)(w8 + SKB_OFF);
  unsigned short* QVb = (unsigned short*)(w8 + QVB_OFF);
  unsigned short* SVb = (unsigned short*)(w8 + SVB_OFF);
  unsigned short* G2 = (unsigned short*)(w8 + G2_OFF);
  unsigned short* SCb = (unsigned short*)(w8 + SCB_OFF);
  unsigned short* G1b = (unsigned short*)(w8 + G1B_OFF);
  float* QNORM = (float*)(w8 + QNORM_OFF);
  int* RANK = (int*)(w8 + RANK_OFF);

  k_pre<<<dim3(NFRAMES + 13824 + 1), dim3(256), 0, stream>>>(support, queries, Wk, Wv,
                                                             labels, APb, WT, RANK, out);
  k_gemm1<<<dim3(432), dim3(256), 0, stream>>>(APb, WT, Pb);
  k_combine<<<dim3(225, 2), dim3(256), 0, stream>>>(Pb, bk, bv, ln_g, ln_b, RANK,
                                                    SKb, QKb, SVb, QVb, QNORM);
  k_rowgemm<<<dim3(998), dim3(256), 0, stream>>>(QKb, SKb, QVb, SVb, SCb, G1b, G2);
  k_attn<<<dim3(175, 5), dim3(256), 0, stream>>>(SCb, G1b, G2, QNORM, out);
}

// Round 6
// 405.580 us; speedup vs baseline: 3.0409x; 3.0409x over previous
//
#include <hip/hip_runtime.h>
#include <math.h>

// ---------------- problem constants ----------------
#define SEQ_LEN 8
#define IN_DIM 2048
#define OUT_DIM 1152
#define NTUP 56
#define NSUP 25
#define NQ 200
#define WAY 5
#define SFRAMES 200
#define NFRAMES 1800
#define SROWS 1400
#define QROWS 11200
#define AT_STRIDE 1440   // bf16 scores/G1 row stride: 5 classes * 288
#define KC 288           // per-class padded K (280 valid + 8 zeros)
#define ALD 296          // attn LDS row stride (shorts)

typedef __attribute__((ext_vector_type(8))) short short8;
typedef __attribute__((ext_vector_type(4))) float f32x4;

__device__ __constant__ int TUP[NTUP][3] = {
{0,1,2},{0,1,3},{0,1,4},{0,1,5},{0,1,6},{0,1,7},
{0,2,3},{0,2,4},{0,2,5},{0,2,6},{0,2,7},
{0,3,4},{0,3,5},{0,3,6},{0,3,7},
{0,4,5},{0,4,6},{0,4,7},
{0,5,6},{0,5,7},
{0,6,7},
{1,2,3},{1,2,4},{1,2,5},{1,2,6},{1,2,7},
{1,3,4},{1,3,5},{1,3,6},{1,3,7},
{1,4,5},{1,4,6},{1,4,7},
{1,5,6},{1,5,7},
{1,6,7},
{2,3,4},{2,3,5},{2,3,6},{2,3,7},
{2,4,5},{2,4,6},{2,4,7},
{2,5,6},{2,5,7},
{2,6,7},
{3,4,5},{3,4,6},{3,4,7},
{3,5,6},{3,5,7},
{3,6,7},
{4,5,6},{4,5,7},
{4,6,7},
{5,6,7}};

// ---------------- bf16 helpers ----------------
__device__ __forceinline__ unsigned short f2bf(float x) {
  union { float f; unsigned int u; } v; v.f = x;
  unsigned int r = v.u + 0x7fffu + ((v.u >> 16) & 1u);
  return (unsigned short)(r >> 16);
}
__device__ __forceinline__ float bf2f(unsigned short s) {
  union { float f; unsigned int u; } v; v.u = ((unsigned int)s) << 16;
  return v.f;
}

// async 16B global -> LDS (dest = wave-uniform base + lane*16; tid-contiguous ok)
__device__ __forceinline__ void gll16(const void* g, void* l) {
  __builtin_amdgcn_global_load_lds(
      (const __attribute__((address_space(1))) unsigned int*)g,
      (__attribute__((address_space(3))) unsigned int*)l, 16, 0, 0);
}

// counted vmcnt wait (T4)
#define VMCNT(N) asm volatile("s_waitcnt vmcnt(" #N ")" ::: "memory")

// raw workgroup barrier WITHOUT the compiler's vmcnt(0) drain
__device__ __forceinline__ void pbar() {
  asm volatile("" ::: "memory");
  __builtin_amdgcn_s_barrier();
  asm volatile("" ::: "memory");
}

// ---------------- workspace byte offsets ----------------
#define APB_OFF   0UL                     // bf16 [1800][2048]
#define WT_OFF    7372800UL               // bf16 [6912][2048]
#define PB_OFF    35684352UL              // bf16 [1800][6912]
#define QKB_OFF   60567552UL              // bf16 [11200][1152]
#define SKB_OFF   86372352UL              // bf16 [1400][1152] class-sorted
#define QVB_OFF   89597952UL              // bf16 [11200][1152]
#define SVB_OFF   115402752UL             // bf16 [1400][1152] class-sorted
#define G2_OFF    118628352UL             // bf16 [5][288][288] Gram
#define SCB_OFF   119457792UL             // bf16 [11200][1440] class-padded
#define G1B_OFF   151713792UL             // bf16 [11200][1440] class-padded
#define QNORM_OFF 183969792UL             // f32  [11200]
#define RANK_OFF  184014592UL             // i32  [25]

// ---------------- k_pre: fused (X+PE)->bf16, weight transpose, rank, out-zero ----------------
__global__ __launch_bounds__(256) void k_pre(const float* __restrict__ S,
                                             const float* __restrict__ Q,
                                             const float* __restrict__ Wk,
                                             const float* __restrict__ Wv,
                                             const int* __restrict__ labels,
                                             unsigned short* __restrict__ APb,
                                             unsigned short* __restrict__ WT,
                                             int* __restrict__ rank,
                                             float* __restrict__ outz) {
  __shared__ float t[32][33];
  int b = blockIdx.x, tid = threadIdx.x;
  if (b < NFRAMES) {
    int frame = b;
    int e8 = tid * 8;
    int pos = frame & 7;
    const float c0 = -logf(10000.0f) / (float)IN_DIM;
    float pe[8];
#pragma unroll
    for (int p = 0; p < 4; ++p) {
      float dt = expf((float)(e8 + 2 * p) * c0);
      float arg = (float)pos * dt;
      pe[2 * p] = sinf(arg) * 0.1f;
      pe[2 * p + 1] = cosf(arg) * 0.1f;
    }
    const float* src = (frame < SFRAMES) ? (S + (size_t)frame * IN_DIM + e8)
                                         : (Q + (size_t)(frame - SFRAMES) * IN_DIM + e8);
    float4 x0 = ((const float4*)src)[0], x1 = ((const float4*)src)[1];
    short8 o;
    o[0] = (short)f2bf(x0.x + pe[0]); o[1] = (short)f2bf(x0.y + pe[1]);
    o[2] = (short)f2bf(x0.z + pe[2]); o[3] = (short)f2bf(x0.w + pe[3]);
    o[4] = (short)f2bf(x1.x + pe[4]); o[5] = (short)f2bf(x1.y + pe[5]);
    o[6] = (short)f2bf(x1.z + pe[6]); o[7] = (short)f2bf(x1.w + pe[7]);
    *(short8*)(APb + (size_t)frame * IN_DIM + e8) = o;
  } else if (b < NFRAMES + 13824) {
    int z = b - NFRAMES;                  // 64 k-tiles x 36 d-tiles x 6 (w,j)
    int bz = z / (64 * 36); int rem = z % (64 * 36);
    int by = rem / 64, bx = rem % 64;
    int w = bz / 3, j = bz % 3;
    const float* W = w ? Wv : Wk;
    int k0 = bx * 32, d0 = by * 32;
    int tx = tid & 31, ty = tid >> 5;
#pragma unroll
    for (int i = 0; i < 4; ++i) {
      int k = k0 + ty + i * 8;
      t[ty + i * 8][tx] = W[(size_t)(j * IN_DIM + k) * OUT_DIM + d0 + tx];
    }
    __syncthreads();
    int colbase = w * 3456 + j * 1152 + d0;
#pragma unroll
    for (int i = 0; i < 4; ++i) {
      int d = ty + i * 8;
      WT[(size_t)(colbase + d) * IN_DIM + k0 + tx] = f2bf(t[tx][d]);
    }
  } else {
    for (int i = tid; i < NQ * WAY; i += 256) outz[i] = 0.f;
    if (tid == 0) {
      for (int s = 0; s < NSUP; ++s) {
        int r = 0;
        for (int s2 = 0; s2 < NSUP; ++s2)
          r += (labels[s2] < labels[s]) || (labels[s2] == labels[s] && s2 < s);
        rank[s] = r;
      }
    }
  }
}

// ---------------- MFMA GEMM core: BM=256 x BN=128, BK=32, 256 thr / 4 waves ----------------
// LDS-throughput fix (round 4 diagnosis): B never touches LDS. B-fragments load
// straight from global (L2-resident panels) into registers, ping-pong bfA/bfB.
// LDS carries A only: 2 x 16 KB buffers, depth-1 gll16 prefetch, chunk-XOR layout
// (0 conflicts). LDS traffic/iter: 72 -> 48 KB; B's 16 KB/iter moves to L2 pipe.
// REGISTER BUDGET (round-5 lesson): gfx950 unified VGPR/AGPR file; this kernel
// needs ~230 regs (acc 128 AGPR + af 32 + bf 32 + addr). __launch_bounds__(256,2)
// => 256-reg cap, NO SPILL. (256,3) capped at ~170 and spilled acc -> 1.3 GB
// scratch traffic. Do not raise the occupancy bound.
// vmcnt: per iter issue {4 A-gll16, 4 B-reg-loads}; end-of-iter VMCNT(4) retires
// exactly A(t+1) (oldest 4) while B(t+1) rides on; compiler inserts its own waits
// before bf register uses.
__device__ __forceinline__ void mfma_core256(const short* __restrict__ A, int lda, int maxA,
                                             const short* __restrict__ B, int ldb, int maxB,
                                             int K, short* lds, f32x4 (&acc)[8][4]) {
  int tid = threadIdx.x;
  int lane = tid & 63, wave = tid >> 6;
  int wm = wave >> 1, wn = wave & 1;
  int col = lane & 15, quad = lane >> 4;
  int kq8 = (quad ^ ((col >> 1) & 3)) * 8;     // read-side swizzled k-chunk (shorts)

  // A staging: 1024 slots (256 rows x 4 chunks), 4 gll16/thread
  int rt_ = tid >> 2;                          // slot row base 0..63
  int qo = ((tid & 3) ^ ((tid >> 3) & 3)) * 8; // inverse-swizzled source chunk
  const short* a0p = A + (size_t)min(rt_,       maxA) * lda + qo;
  const short* a1p = A + (size_t)min(rt_ + 64,  maxA) * lda + qo;
  const short* a2p = A + (size_t)min(rt_ + 128, maxA) * lda + qo;
  const short* a3p = A + (size_t)min(rt_ + 192, maxA) * lda + qo;
  // B per-lane direct global pointers (no LDS)
  const short* bp0 = B + (size_t)min(wn * 64 + col,      maxB) * ldb + quad * 8;
  const short* bp1 = B + (size_t)min(wn * 64 + 16 + col, maxB) * ldb + quad * 8;
  const short* bp2 = B + (size_t)min(wn * 64 + 32 + col, maxB) * ldb + quad * 8;
  const short* bp3 = B + (size_t)min(wn * 64 + 48 + col, maxB) * ldb + quad * 8;
  const int nt = K >> 5;                       // even at all call sites (36 or 64)

#define STAGEA(t, cb)                                \
  do {                                               \
    short* buf_ = lds + (cb);                        \
    int k0_ = (t) << 5;                              \
    gll16(a0p + k0_, buf_ + (size_t)tid * 8);        \
    gll16(a1p + k0_, buf_ + (size_t)(tid + 256) * 8);\
    gll16(a2p + k0_, buf_ + (size_t)(tid + 512) * 8);\
    gll16(a3p + k0_, buf_ + (size_t)(tid + 768) * 8);\
  } while (0)
#define LOADB(dst, t)                                \
  do {                                               \
    int k0_ = (t) << 5;                              \
    dst[0] = *(const short8*)(bp0 + k0_);            \
    dst[1] = *(const short8*)(bp1 + k0_);            \
    dst[2] = *(const short8*)(bp2 + k0_);            \
    dst[3] = *(const short8*)(bp3 + k0_);            \
  } while (0)
#define MFMA16(BF)                                                                     \
  do {                                                                                 \
    short8 af[8];                                                                      \
    _Pragma("unroll")                                                                  \
    for (int i = 0; i < 8; ++i)                                                        \
      af[i] = *(const short8*)(As + (wm * 128 + i * 16 + col) * 32 + kq8);             \
    __builtin_amdgcn_s_setprio(1);                                                     \
    _Pragma("unroll")                                                                  \
    for (int i = 0; i < 8; ++i)                                                        \
      _Pragma("unroll")                                                                \
      for (int j = 0; j < 4; ++j)                                                      \
        acc[i][j] = __builtin_amdgcn_mfma_f32_16x16x32_bf16(af[i], BF[j], acc[i][j],   \
                                                            0, 0, 0);                  \
    __builtin_amdgcn_s_setprio(0);                                                     \
  } while (0)

  short8 bfA[4], bfB[4];
  // prologue: A(0) staged (oldest), B(0) regs; VMCNT(4) retires A(0), B(0) rides
  STAGEA(0, 0);
  LOADB(bfA, 0);
  VMCNT(4);
  pbar();
  for (int t = 0; t < nt; t += 2) {
    {   // ---- even sub-iter: compute buf0 x bfA; stage A(t+1)->buf1; load bfB ----
      STAGEA(t + 1, 8192);                   // t+1 < nt always (nt even)
      LOADB(bfB, t + 1);
      const short* As = lds;
      MFMA16(bfA);
      VMCNT(4);                              // A(t+1) landed; B(t+1) in flight
      pbar();
    }
    {   // ---- odd sub-iter u = t+1: compute buf1 x bfB; stage A(u+1)->buf0 ----
      int u = t + 1;
      if (u + 1 < nt) { STAGEA(u + 1, 0); LOADB(bfA, u + 1); }
      const short* As = lds + 8192;
      MFMA16(bfB);
      if (u + 1 < nt) { VMCNT(4); pbar(); }
      // last sub-iter: nothing issued, no LDS reuse after -> no wait/barrier
    }
  }
#undef STAGEA
#undef LOADB
#undef MFMA16
}

// ---------------- GEMM1: Pb[1800][6912] = APb @ WT^T (256x128 tiles) ----------------
__global__ __launch_bounds__(256, 2) void k_gemm1(const unsigned short* __restrict__ APb,
                                                  const unsigned short* __restrict__ WT,
                                                  unsigned short* __restrict__ Pb) {
  __shared__ short lds[16384];           // 2 x 16KB A-pipeline buffers
  int o = blockIdx.x;                    // 432 blocks; XCD swizzle (432 % 8 == 0)
  int L = (o & 7) * 54 + (o >> 3);
  int rt = L / 54, ct = L % 54;
  int row0 = rt << 8, col0 = ct << 7;
  f32x4 acc[8][4];
#pragma unroll
  for (int i = 0; i < 8; ++i)
#pragma unroll
    for (int j = 0; j < 4; ++j) acc[i][j] = (f32x4)(0.f);
  mfma_core256((const short*)APb + (size_t)row0 * IN_DIM, IN_DIM, min(255, NFRAMES - 1 - row0),
               (const short*)WT + (size_t)col0 * IN_DIM, IN_DIM, 127,
               IN_DIM, lds, acc);
  int lane = threadIdx.x & 63, wave = threadIdx.x >> 6;
  int wm = wave >> 1, wn = wave & 1, col = lane & 15, quad = lane >> 4;
#pragma unroll
  for (int i = 0; i < 8; ++i)
#pragma unroll
    for (int r = 0; r < 4; ++r) {
      int gr = row0 + wm * 128 + i * 16 + quad * 4 + r;
      if (gr >= NFRAMES) continue;
#pragma unroll
      for (int j = 0; j < 4; ++j)
        Pb[(size_t)gr * 6912 + col0 + wn * 64 + j * 16 + col] = f2bf(acc[i][j][r]);
    }
}

// ---------------- combine (clip-LDS): one block per (clip, k/v) ----------------
__global__ __launch_bounds__(256) void k_combine(const unsigned short* __restrict__ Pb,
                                                 const float* __restrict__ bk,
                                                 const float* __restrict__ bv,
                                                 const float* __restrict__ g,
                                                 const float* __restrict__ bb,
                                                 const int* __restrict__ rank,
                                                 unsigned short* __restrict__ SKb,
                                                 unsigned short* __restrict__ QKb,
                                                 unsigned short* __restrict__ SVb,
                                                 unsigned short* __restrict__ QVb,
                                                 float* __restrict__ qnorm) {
  __shared__ short L[8 * 3456];
  int n = blockIdx.x, w = blockIdx.y;
  int tid = threadIdx.x;
  bool sup = n < NSUP;
  int fbase = sup ? n * SEQ_LEN : SFRAMES + (n - NSUP) * SEQ_LEN;
  for (int i = 0; i < 14; ++i) {
    int idx = tid + 256 * i;          // vec8 index < 3456
    if (idx < 3456) {
      int fr = idx / 432, off = (idx - fr * 432) * 8;
      *(short8*)(L + fr * 3456 + off) =
          *(const short8*)(Pb + (size_t)(fbase + fr) * 6912 + w * 3456 + off);
    }
  }
  __syncthreads();
  int wave = tid >> 6, lane = tid & 63;
  const float* bias = w ? bv : bk;
  float2 bi[9], gg[9], bbv[9];
#pragma unroll
  for (int i = 0; i < 9; ++i) {
    int p = lane + 64 * i;
    bi[i] = *(const float2*)(bias + 2 * p);
    if (w == 0) {
      gg[i] = *(const float2*)(g + 2 * p);
      bbv[i] = *(const float2*)(bb + 2 * p);
    }
  }
  int obase = sup ? rank[n] * NTUP : (n - NSUP) * NTUP;
  const unsigned int* Lu = (const unsigned int*)L;
  for (int t = wave; t < NTUP; t += 4) {
    int b0 = (TUP[t][0] * 3456) >> 1;
    int b1 = (TUP[t][1] * 3456 + 1152) >> 1;
    int b2 = (TUP[t][2] * 3456 + 2304) >> 1;
    float va[18];
    float sum = 0.f, sq = 0.f;
#pragma unroll
    for (int i = 0; i < 9; ++i) {
      int p = lane + 64 * i;
      unsigned int u0 = Lu[b0 + p], u1 = Lu[b1 + p], u2 = Lu[b2 + p];
      float a = bf2f((unsigned short)u0) + bf2f((unsigned short)u1) +
                bf2f((unsigned short)u2) + bi[i].x;
      float b = bf2f((unsigned short)(u0 >> 16)) + bf2f((unsigned short)(u1 >> 16)) +
                bf2f((unsigned short)(u2 >> 16)) + bi[i].y;
      va[2 * i] = a; va[2 * i + 1] = b;
      sum += a + b;
      sq += a * a + b * b;
    }
#pragma unroll
    for (int o = 32; o; o >>= 1) {
      sum += __shfl_xor(sum, o);
      sq += __shfl_xor(sq, o);
    }
    int orow = obase + t;
    if (w == 0) {
      float mean = sum * (1.f / OUT_DIM);
      float var = sq * (1.f / OUT_DIM) - mean * mean;
      float inv = rsqrtf(var + 1e-5f);
      unsigned short* outp = (sup ? SKb : QKb) + (size_t)orow * OUT_DIM;
#pragma unroll
      for (int i = 0; i < 9; ++i) {
        int p = lane + 64 * i;
        unsigned int lo = f2bf((va[2 * i] - mean) * inv * gg[i].x + bbv[i].x);
        unsigned int hi = f2bf((va[2 * i + 1] - mean) * inv * gg[i].y + bbv[i].y);
        *(unsigned int*)(outp + 2 * p) = lo | (hi << 16);
      }
    } else {
      unsigned short* outp = (sup ? SVb : QVb) + (size_t)orow * OUT_DIM;
#pragma unroll
      for (int i = 0; i < 9; ++i) {
        int p = lane + 64 * i;
        unsigned int lo = f2bf(va[2 * i]);
        unsigned int hi = f2bf(va[2 * i + 1]);
        *(unsigned int*)(outp + 2 * p) = lo | (hi << 16);
      }
      if (!sup && lane == 0) qnorm[orow] = sq;
    }
  }
}

// ---------------- merged: scores / G1 + Gram G2 (256x128 tiles) ----------------
// 998 blocks: 968 scores/G1 (44 rt x 11 ct x 2) + 30 G2 (5 classes x 2 rt x 3 ct)
__global__ __launch_bounds__(256, 2) void k_rowgemm(const unsigned short* __restrict__ QKb,
                                                    const unsigned short* __restrict__ SKb,
                                                    const unsigned short* __restrict__ QVb,
                                                    const unsigned short* __restrict__ SVb,
                                                    unsigned short* __restrict__ SCb,
                                                    unsigned short* __restrict__ G1b,
                                                    unsigned short* __restrict__ G2) {
  __shared__ short lds[16384];           // 2 x 16KB A-pipeline buffers
  int o = blockIdx.x;                    // bijective XCD swizzle for nwg=998 (q=124,r=6)
  int xcd = o & 7, idx = o >> 3;
  int L = (xcd < 6 ? xcd * 125 : 750 + (xcd - 6) * 124) + idx;
  f32x4 acc[8][4];
#pragma unroll
  for (int i = 0; i < 8; ++i)
#pragma unroll
    for (int j = 0; j < 4; ++j) acc[i][j] = (f32x4)(0.f);
  int lane = threadIdx.x & 63, wave = threadIdx.x >> 6;
  int wm = wave >> 1, wn = wave & 1, col = lane & 15, quad = lane >> 4;

  if (L < 968) {
    int g1 = L >= 484; int l = g1 ? L - 484 : L;
    int rt = l / 11, ct = l % 11;
    int row0 = rt << 8, col0 = ct << 7;
    const unsigned short* Am = g1 ? QVb : QKb;
    const unsigned short* Bm = g1 ? SVb : SKb;
    mfma_core256((const short*)Am + (size_t)row0 * OUT_DIM, OUT_DIM, min(255, QROWS - 1 - row0),
                 (const short*)Bm + (size_t)col0 * OUT_DIM, OUT_DIM, min(127, SROWS - 1 - col0),
                 OUT_DIM, lds, acc);
    unsigned short* outp = g1 ? G1b : SCb;
    const float scl = g1 ? 1.0f : 0.029462782549439483f;  // 1/sqrt(1152)
#pragma unroll
    for (int i = 0; i < 8; ++i)
#pragma unroll
      for (int r = 0; r < 4; ++r) {
        int gr = row0 + wm * 128 + i * 16 + quad * 4 + r;
        if (gr >= QROWS) continue;
#pragma unroll
        for (int j = 0; j < 4; ++j) {
          int gc = col0 + wn * 64 + j * 16 + col;
          if (gc < SROWS) {
            int c = gc / 280;
            outp[(size_t)gr * AT_STRIDE + gc + c * 8] = f2bf(acc[i][j][r] * scl);
          }
        }
      }
  } else {
    int l = L - 968;                  // 0..29: G2[c] = SV_c @ SV_c^T
    int c = l / 6, rem = l % 6;
    int rt = rem / 3, ct = rem % 3;
    int i0 = rt << 8, j0 = ct << 7;
    const short* base = (const short*)SVb + (size_t)c * 280 * OUT_DIM;
    mfma_core256(base + (size_t)i0 * OUT_DIM, OUT_DIM, 279 - i0,
                 base + (size_t)j0 * OUT_DIM, OUT_DIM, min(127, 279 - j0),
                 OUT_DIM, lds, acc);
    unsigned short* g2c = G2 + (size_t)c * KC * KC;
#pragma unroll
    for (int i = 0; i < 8; ++i)
#pragma unroll
      for (int r = 0; r < 4; ++r) {
        int gi = i0 + wm * 128 + i * 16 + quad * 4 + r;
        if (gi >= KC) continue;
#pragma unroll
        for (int j = 0; j < 4; ++j) {
          int gj = j0 + wn * 64 + j * 16 + col;
          if (gj < KC) g2c[(size_t)gi * KC + gj] = f2bf(acc[i][j][r]);
        }
      }
  }
}

// ---------------- k_attn: fused softmax + T2 + T3 (= e^T G2 e / S^2) + out atomics ----------------
__global__ __launch_bounds__(256) void k_attn(const unsigned short* __restrict__ SCb,
                                              const unsigned short* __restrict__ G1b,
                                              const unsigned short* __restrict__ G2,
                                              const float* __restrict__ qnorm,
                                              float* __restrict__ out) {
  __shared__ short attn[64 * ALD];     // 37,888 B
  __shared__ short Bs[64 * KC];        // 36,864 B
  __shared__ float T2n[64];
  __shared__ float Sarr[64];
  __shared__ float rowsum[64];
  __shared__ float val[64];
  int r0 = blockIdx.x * 64, c = blockIdx.y;
  int tid = threadIdx.x;

  // ---- phase 1: softmax numerators e = exp(s - M) -> LDS; S and T2 numerator ----
  int lr = tid >> 2, h = tid & 3;
  const unsigned short* ps = SCb + (size_t)(r0 + lr) * AT_STRIDE + c * KC;
  const unsigned short* pg = G1b + (size_t)(r0 + lr) * AT_STRIDE + c * KC;
  short8 sv[9];
  float mx = -INFINITY;
#pragma unroll
  for (int i = 0; i < 9; ++i) {
    int v = h * 9 + i;
    if (v < 35) {
      sv[i] = *(const short8*)(ps + v * 8);
#pragma unroll
      for (int j = 0; j < 8; ++j) mx = fmaxf(mx, bf2f((unsigned short)sv[i][j]));
    }
  }
  mx = fmaxf(mx, __shfl_xor(mx, 1));
  mx = fmaxf(mx, __shfl_xor(mx, 2));
  float sum = 0.f, t2 = 0.f;
#pragma unroll
  for (int i = 0; i < 9; ++i) {
    int v = h * 9 + i;
    if (v < 35) {
      short8 gv8 = *(const short8*)(pg + v * 8);
      short8 e8;
#pragma unroll
      for (int j = 0; j < 8; ++j) {
        float e = __expf(bf2f((unsigned short)sv[i][j]) - mx);
        sum += e;
        t2 += e * bf2f((unsigned short)gv8[j]);
        e8[j] = (short)f2bf(e);
      }
      *(short8*)(attn + lr * ALD + v * 8) = e8;
    } else {
      *(short8*)(attn + lr * ALD + v * 8) = (short8)0;   // zero class pad (v == 35)
    }
  }
  sum += __shfl_xor(sum, 1); sum += __shfl_xor(sum, 2);
  t2 += __shfl_xor(t2, 1); t2 += __shfl_xor(t2, 2);
  if (h == 0) { Sarr[lr] = sum; T2n[lr] = t2; }
  if (tid < 64) rowsum[tid] = 0.f;
  __syncthreads();

  // ---- phase 2: B2 = e @ G2 per 64-col slab; B staged full-K once per slab ----
  int lane = tid & 63, wave = tid >> 6;
  int col = lane & 15, quad = lane >> 4;
  const short* G2c = (const short*)G2 + (size_t)c * KC * KC;
  float part[4][4] = {};
  for (int j0 = 0; j0 < KC; j0 += 64) {
    int ncols = min(64, KC - j0);            // 64,64,64,64,32
    int chunks = ncols * 36;                 // 16-B chunks: 2304 or 1152
    for (int base = 0; base < chunks; base += 256) {
      int idx = base + tid;
      if (idx < chunks) {
        int n = idx / 36, kk = idx - n * 36;
        gll16(G2c + (size_t)(j0 + n) * KC + kk * 8, Bs + idx * 8);
      }
    }
    __syncthreads();
    if (wave * 16 < ncols) {
      f32x4 acc[4];
#pragma unroll
      for (int i = 0; i < 4; ++i) acc[i] = (f32x4)(0.f);
      for (int kq = 0; kq < 9; ++kq) {
        short8 bf = *(const short8*)(Bs + (wave * 16 + col) * KC + kq * 32 + quad * 8);
#pragma unroll
        for (int i = 0; i < 4; ++i) {
          short8 af = *(const short8*)(attn + (i * 16 + col) * ALD + kq * 32 + quad * 8);
          acc[i] = __builtin_amdgcn_mfma_f32_16x16x32_bf16(af, bf, acc[i], 0, 0, 0);
        }
      }
      int gcol = j0 + wave * 16 + col;
#pragma unroll
      for (int i = 0; i < 4; ++i)
#pragma unroll
        for (int r = 0; r < 4; ++r)
          part[i][r] += bf2f((unsigned short)attn[(i * 16 + quad * 4 + r) * ALD + gcol]) *
                        acc[i][r];
    }
    __syncthreads();
  }
  // reduce rowdot across the wave's 16 cols, then across waves via LDS atomics
#pragma unroll
  for (int i = 0; i < 4; ++i)
#pragma unroll
    for (int r = 0; r < 4; ++r) {
      float s = part[i][r];
      s += __shfl_xor(s, 1); s += __shfl_xor(s, 2);
      s += __shfl_xor(s, 4); s += __shfl_xor(s, 8);
      if (col == 0) atomicAdd(&rowsum[i * 16 + quad * 4 + r], s);
    }
  __syncthreads();

  // ---- phase 3: per-row distance, per-query reduce, one atomic per (q, c) ----
  if (tid < 64) {
    float S = Sarr[tid], invS = 1.f / S;
    val[tid] = qnorm[r0 + tid] - 2.f * T2n[tid] * invS + rowsum[tid] * invS * invS;
  }
  __syncthreads();
  if (tid < 3) {
    int q = r0 / NTUP + tid;
    int lo = max(q * NTUP, r0), hi = min(q * NTUP + NTUP, r0 + 64);
    if (lo < hi && q < NQ) {
      float s = 0.f;
      for (int r = lo; r < hi; ++r) s += val[r - r0];
      atomicAdd(&out[q * WAY + c], -s * (1.f / NTUP));
    }
  }
}

// ---------------- launch ----------------
extern "C" void kernel_launch(void* const* d_in, const int* in_sizes, int n_in,
                              void* d_out, int out_size, void* d_ws, size_t ws_size,
                              hipStream_t stream) {
  const float* support = (const float*)d_in[0];
  const int* labels = (const int*)d_in[1];
  const float* queries = (const float*)d_in[2];
  const float* Wk = (const float*)d_in[3];
  const float* bk = (const float*)d_in[4];
  const float* Wv = (const float*)d_in[5];
  const float* bv = (const float*)d_in[6];
  const float* ln_g = (const float*)d_in[7];
  const float* ln_b = (const float*)d_in[8];
  float* out = (float*)d_out;
  char* w8 = (char*)d_ws;

  unsigned short* APb = (unsigned short*)(w8 + APB_OFF);
  unsigned short* WT = (unsigned short*)(w8 + WT_OFF);
  unsigned short* Pb = (unsigned short*)(w8 + PB_OFF);
  unsigned short* QKb = (unsigned short*)(w8 + QKB_OFF);
  unsigned short* SKb = (unsigned short*)(w8 + SKB_OFF);
  unsigned short* QVb = (unsigned short*)(w8 + QVB_OFF);
  unsigned short* SVb = (unsigned short*)(w8 + SVB_OFF);
  unsigned short* G2 = (unsigned short*)(w8 + G2_OFF);
  unsigned short* SCb = (unsigned short*)(w8 + SCB_OFF);
  unsigned short* G1b = (unsigned short*)(w8 + G1B_OFF);
  float* QNORM = (float*)(w8 + QNORM_OFF);
  int* RANK = (int*)(w8 + RANK_OFF);

  k_pre<<<dim3(NFRAMES + 13824 + 1), dim3(256), 0, stream>>>(support, queries, Wk, Wv,
                                                             labels, APb, WT, RANK, out);
  k_gemm1<<<dim3(432), dim3(256), 0, stream>>>(APb, WT, Pb);
  k_combine<<<dim3(225, 2), dim3(256), 0, stream>>>(Pb, bk, bv, ln_g, ln_b, RANK,
                                                    SKb, QKb, SVb, QVb, QNORM);
  k_rowgemm<<<dim3(998), dim3(256), 0, stream>>>(QKb, SKb, QVb, SVb, SCb, G1b, G2);
  k_attn<<<dim3(175, 5), dim3(256), 0, stream>>>(SCb, G1b, G2, QNORM, out);
}

// Round 7
// 354.660 us; speedup vs baseline: 3.4775x; 1.1436x over previous
//
#include <hip/hip_runtime.h>
#include <math.h>

// ---------------- problem constants ----------------
#define SEQ_LEN 8
#define IN_DIM 2048
#define OUT_DIM 1152
#define NTUP 56
#define NSUP 25
#define NQ 200
#define WAY 5
#define SFRAMES 200
#define NFRAMES 1800
#define SROWS 1400
#define QROWS 11200
#define AT_STRIDE 1440   // bf16 scores/G1 row stride: 5 classes * 288
#define KC 288           // per-class padded K (280 valid + 8 zeros)
#define ALD 296          // attn LDS row stride (shorts)

typedef __attribute__((ext_vector_type(8))) short short8;
typedef __attribute__((ext_vector_type(4))) float f32x4;

__device__ __constant__ int TUP[NTUP][3] = {
{0,1,2},{0,1,3},{0,1,4},{0,1,5},{0,1,6},{0,1,7},
{0,2,3},{0,2,4},{0,2,5},{0,2,6},{0,2,7},
{0,3,4},{0,3,5},{0,3,6},{0,3,7},
{0,4,5},{0,4,6},{0,4,7},
{0,5,6},{0,5,7},
{0,6,7},
{1,2,3},{1,2,4},{1,2,5},{1,2,6},{1,2,7},
{1,3,4},{1,3,5},{1,3,6},{1,3,7},
{1,4,5},{1,4,6},{1,4,7},
{1,5,6},{1,5,7},
{1,6,7},
{2,3,4},{2,3,5},{2,3,6},{2,3,7},
{2,4,5},{2,4,6},{2,4,7},
{2,5,6},{2,5,7},
{2,6,7},
{3,4,5},{3,4,6},{3,4,7},
{3,5,6},{3,5,7},
{3,6,7},
{4,5,6},{4,5,7},
{4,6,7},
{5,6,7}};

// ---------------- bf16 helpers ----------------
__device__ __forceinline__ unsigned short f2bf(float x) {
  union { float f; unsigned int u; } v; v.f = x;
  unsigned int r = v.u + 0x7fffu + ((v.u >> 16) & 1u);
  return (unsigned short)(r >> 16);
}
__device__ __forceinline__ float bf2f(unsigned short s) {
  union { float f; unsigned int u; } v; v.u = ((unsigned int)s) << 16;
  return v.f;
}

// async 16B global -> LDS (dest = wave-uniform base + lane*16; tid-contiguous ok)
__device__ __forceinline__ void gll16(const void* g, void* l) {
  __builtin_amdgcn_global_load_lds(
      (const __attribute__((address_space(1))) unsigned int*)g,
      (__attribute__((address_space(3))) unsigned int*)l, 16, 0, 0);
}

// counted vmcnt wait (T4)
#define VMCNT(N) asm volatile("s_waitcnt vmcnt(" #N ")" ::: "memory")

// raw workgroup barrier WITHOUT the compiler's vmcnt(0) drain
__device__ __forceinline__ void pbar() {
  asm volatile("" ::: "memory");
  __builtin_amdgcn_s_barrier();
  asm volatile("" ::: "memory");
}

// ---------------- workspace byte offsets ----------------
#define APB_OFF   0UL                     // bf16 [1800][2048]
#define WT_OFF    7372800UL               // bf16 [6912][2048]
#define PB_OFF    35684352UL              // bf16 [1800][6912]
#define QKB_OFF   60567552UL              // bf16 [11200][1152]
#define SKB_OFF   86372352UL              // bf16 [1400][1152] class-sorted
#define QVB_OFF   89597952UL              // bf16 [11200][1152]
#define SVB_OFF   115402752UL             // bf16 [1400][1152] class-sorted
#define G2_OFF    118628352UL             // bf16 [5][288][288] Gram
#define SCB_OFF   119457792UL             // bf16 [11200][1440] class-padded
#define G1B_OFF   151713792UL             // bf16 [11200][1440] class-padded
#define QNORM_OFF 183969792UL             // f32  [11200]
#define RANK_OFF  184014592UL             // i32  [25]

// ---------------- k_pre: fused (X+PE)->bf16, weight transpose, rank, out-zero ----------------
__global__ __launch_bounds__(256) void k_pre(const float* __restrict__ S,
                                             const float* __restrict__ Q,
                                             const float* __restrict__ Wk,
                                             const float* __restrict__ Wv,
                                             const int* __restrict__ labels,
                                             unsigned short* __restrict__ APb,
                                             unsigned short* __restrict__ WT,
                                             int* __restrict__ rank,
                                             float* __restrict__ outz) {
  __shared__ float t[32][33];
  int b = blockIdx.x, tid = threadIdx.x;
  if (b < NFRAMES) {
    int frame = b;
    int e8 = tid * 8;
    int pos = frame & 7;
    const float c0 = -logf(10000.0f) / (float)IN_DIM;
    float pe[8];
#pragma unroll
    for (int p = 0; p < 4; ++p) {
      float dt = expf((float)(e8 + 2 * p) * c0);
      float arg = (float)pos * dt;
      pe[2 * p] = sinf(arg) * 0.1f;
      pe[2 * p + 1] = cosf(arg) * 0.1f;
    }
    const float* src = (frame < SFRAMES) ? (S + (size_t)frame * IN_DIM + e8)
                                         : (Q + (size_t)(frame - SFRAMES) * IN_DIM + e8);
    float4 x0 = ((const float4*)src)[0], x1 = ((const float4*)src)[1];
    short8 o;
    o[0] = (short)f2bf(x0.x + pe[0]); o[1] = (short)f2bf(x0.y + pe[1]);
    o[2] = (short)f2bf(x0.z + pe[2]); o[3] = (short)f2bf(x0.w + pe[3]);
    o[4] = (short)f2bf(x1.x + pe[4]); o[5] = (short)f2bf(x1.y + pe[5]);
    o[6] = (short)f2bf(x1.z + pe[6]); o[7] = (short)f2bf(x1.w + pe[7]);
    *(short8*)(APb + (size_t)frame * IN_DIM + e8) = o;
  } else if (b < NFRAMES + 13824) {
    int z = b - NFRAMES;                  // 64 k-tiles x 36 d-tiles x 6 (w,j)
    int bz = z / (64 * 36); int rem = z % (64 * 36);
    int by = rem / 64, bx = rem % 64;
    int w = bz / 3, j = bz % 3;
    const float* W = w ? Wv : Wk;
    int k0 = bx * 32, d0 = by * 32;
    int tx = tid & 31, ty = tid >> 5;
#pragma unroll
    for (int i = 0; i < 4; ++i) {
      int k = k0 + ty + i * 8;
      t[ty + i * 8][tx] = W[(size_t)(j * IN_DIM + k) * OUT_DIM + d0 + tx];
    }
    __syncthreads();
    int colbase = w * 3456 + j * 1152 + d0;
#pragma unroll
    for (int i = 0; i < 4; ++i) {
      int d = ty + i * 8;
      WT[(size_t)(colbase + d) * IN_DIM + k0 + tx] = f2bf(t[tx][d]);
    }
  } else {
    for (int i = tid; i < NQ * WAY; i += 256) outz[i] = 0.f;
    if (tid == 0) {
      for (int s = 0; s < NSUP; ++s) {
        int r = 0;
        for (int s2 = 0; s2 < NSUP; ++s2)
          r += (labels[s2] < labels[s]) || (labels[s2] == labels[s] && s2 < s);
        rank[s] = r;
      }
    }
  }
}

// ---------------- MFMA GEMM core: BM=256 x BN=128, BK=32, 256 thr / 4 waves ----------------
// Round-4 proven config (best measured: k_rowgemm 96 us, total 345.7). Chunk-XOR
// layout (0 bank conflicts), depth-2 prefetch over 3 x 24KB LDS buffers, single
// barrier per iter, counted vmcnt(6). REGISTER BUDGET (round-5 lesson): needs
// ~230 unified VGPR/AGPR; __launch_bounds__(256,2) => 256-reg cap, no spill.
// (256,3) spilled acc -> 1.3 GB scratch traffic. Round-6 lesson: B through
// registers/global instead of LDS is SLOWER (L2 latency in MFMA dep chain).
__device__ __forceinline__ void mfma_core256(const short* __restrict__ A, int lda, int maxA,
                                             const short* __restrict__ B, int ldb, int maxB,
                                             int K, short* lds, f32x4 (&acc)[8][4]) {
  int tid = threadIdx.x;
  int lane = tid & 63, wave = tid >> 6;
  int wm = wave >> 1, wn = wave & 1;
  int col = lane & 15, quad = lane >> 4;
  int kq8 = (quad ^ ((col >> 1) & 3)) * 8;     // read-side swizzled k-chunk (shorts)

  // staging: A = 1024 slots (256 rows x 4 chunks), B = 512 slots; 6 gll16/thread
  int rt_ = tid >> 2;                          // slot row base 0..63
  int qo = ((tid & 3) ^ ((tid >> 3) & 3)) * 8; // inverse-swizzled source chunk
  const short* a0p = A + (size_t)min(rt_,       maxA) * lda + qo;
  const short* a1p = A + (size_t)min(rt_ + 64,  maxA) * lda + qo;
  const short* a2p = A + (size_t)min(rt_ + 128, maxA) * lda + qo;
  const short* a3p = A + (size_t)min(rt_ + 192, maxA) * lda + qo;
  const short* b0p = B + (size_t)min(rt_,       maxB) * ldb + qo;
  const short* b1p = B + (size_t)min(rt_ + 64,  maxB) * ldb + qo;
  const int nt = K >> 5;

#define STAGE(t, cb)                                 \
  do {                                               \
    short* buf_ = lds + (cb);                        \
    int k0_ = (t) << 5;                              \
    gll16(a0p + k0_, buf_ + (size_t)tid * 8);        \
    gll16(a1p + k0_, buf_ + (size_t)(tid + 256) * 8);\
    gll16(a2p + k0_, buf_ + (size_t)(tid + 512) * 8);\
    gll16(a3p + k0_, buf_ + (size_t)(tid + 768) * 8);\
    gll16(b0p + k0_, buf_ + 8192 + (size_t)tid * 8); \
    gll16(b1p + k0_, buf_ + 8192 + (size_t)(tid + 256) * 8);\
  } while (0)

  // prologue: tiles 0,1 in flight; confirm tile 0 only (tile 1's 6 ride on)
  STAGE(0, 0);
  STAGE(1, 12288);
  VMCNT(6);
  pbar();
  int c0 = 0, c1 = 12288, c2 = 24576;          // rotating buffer offsets (shorts)
  for (int t = 0; t < nt; ++t) {
    if (t + 2 < nt) STAGE(t + 2, c2);          // depth-2 prefetch into stale buffer
    const short* As = lds + c0;
    const short* Bs = As + 8192;
    short8 af[8], bf[4];
#pragma unroll
    for (int i = 0; i < 8; ++i)
      af[i] = *(const short8*)(As + (wm * 128 + i * 16 + col) * 32 + kq8);
#pragma unroll
    for (int j = 0; j < 4; ++j)
      bf[j] = *(const short8*)(Bs + (wn * 64 + j * 16 + col) * 32 + kq8);
    __builtin_amdgcn_s_setprio(1);
#pragma unroll
    for (int i = 0; i < 8; ++i)
#pragma unroll
      for (int j = 0; j < 4; ++j)
        acc[i][j] = __builtin_amdgcn_mfma_f32_16x16x32_bf16(af[i], bf[j], acc[i][j], 0, 0, 0);
    __builtin_amdgcn_s_setprio(0);
    if (t + 2 < nt)      VMCNT(6);             // tile t+1 landed; t+2 stays in flight
    else if (t + 1 < nt) VMCNT(0);             // epilogue drain (once)
    pbar();                                    // single barrier per iter
    int tmp = c0; c0 = c1; c1 = c2; c2 = tmp;
  }
#undef STAGE
}

// ---------------- GEMM1: Pb[1800][6912] = APb @ WT^T (256x128 tiles) ----------------
__global__ __launch_bounds__(256, 2) void k_gemm1(const unsigned short* __restrict__ APb,
                                                  const unsigned short* __restrict__ WT,
                                                  unsigned short* __restrict__ Pb) {
  __shared__ short lds[36864];           // 3 x 24KB pipeline buffers
  int o = blockIdx.x;                    // 432 blocks; XCD swizzle (432 % 8 == 0)
  int L = (o & 7) * 54 + (o >> 3);
  int rt = L / 54, ct = L % 54;
  int row0 = rt << 8, col0 = ct << 7;
  f32x4 acc[8][4];
#pragma unroll
  for (int i = 0; i < 8; ++i)
#pragma unroll
    for (int j = 0; j < 4; ++j) acc[i][j] = (f32x4)(0.f);
  mfma_core256((const short*)APb + (size_t)row0 * IN_DIM, IN_DIM, min(255, NFRAMES - 1 - row0),
               (const short*)WT + (size_t)col0 * IN_DIM, IN_DIM, 127,
               IN_DIM, lds, acc);
  int lane = threadIdx.x & 63, wave = threadIdx.x >> 6;
  int wm = wave >> 1, wn = wave & 1, col = lane & 15, quad = lane >> 4;
#pragma unroll
  for (int i = 0; i < 8; ++i)
#pragma unroll
    for (int r = 0; r < 4; ++r) {
      int gr = row0 + wm * 128 + i * 16 + quad * 4 + r;
      if (gr >= NFRAMES) continue;
#pragma unroll
      for (int j = 0; j < 4; ++j)
        Pb[(size_t)gr * 6912 + col0 + wn * 64 + j * 16 + col] = f2bf(acc[i][j][r]);
    }
}

// ---------------- combine (clip-LDS): block per (clip, k/v, tuple-half) ----------------
__global__ __launch_bounds__(256) void k_combine(const unsigned short* __restrict__ Pb,
                                                 const float* __restrict__ bk,
                                                 const float* __restrict__ bv,
                                                 const float* __restrict__ g,
                                                 const float* __restrict__ bb,
                                                 const int* __restrict__ rank,
                                                 unsigned short* __restrict__ SKb,
                                                 unsigned short* __restrict__ QKb,
                                                 unsigned short* __restrict__ SVb,
                                                 unsigned short* __restrict__ QVb,
                                                 float* __restrict__ qnorm) {
  __shared__ short L[8 * 3456];
  int n = blockIdx.x, w = blockIdx.y;
  int thalf = blockIdx.z;               // tuple halves: 0 -> [0,28), 1 -> [28,56)
  int tid = threadIdx.x;
  bool sup = n < NSUP;
  int fbase = sup ? n * SEQ_LEN : SFRAMES + (n - NSUP) * SEQ_LEN;
  for (int i = 0; i < 14; ++i) {
    int idx = tid + 256 * i;          // vec8 index < 3456
    if (idx < 3456) {
      int fr = idx / 432, off = (idx - fr * 432) * 8;
      *(short8*)(L + fr * 3456 + off) =
          *(const short8*)(Pb + (size_t)(fbase + fr) * 6912 + w * 3456 + off);
    }
  }
  __syncthreads();
  int wave = tid >> 6, lane = tid & 63;
  const float* bias = w ? bv : bk;
  float2 bi[9], gg[9], bbv[9];
#pragma unroll
  for (int i = 0; i < 9; ++i) {
    int p = lane + 64 * i;
    bi[i] = *(const float2*)(bias + 2 * p);
    if (w == 0) {
      gg[i] = *(const float2*)(g + 2 * p);
      bbv[i] = *(const float2*)(bb + 2 * p);
    }
  }
  int obase = sup ? rank[n] * NTUP : (n - NSUP) * NTUP;
  const unsigned int* Lu = (const unsigned int*)L;
  int tEnd = thalf * 28 + 28;
  for (int t = thalf * 28 + wave; t < tEnd; t += 4) {
    int b0 = (TUP[t][0] * 3456) >> 1;
    int b1 = (TUP[t][1] * 3456 + 1152) >> 1;
    int b2 = (TUP[t][2] * 3456 + 2304) >> 1;
    float va[18];
    float sum = 0.f, sq = 0.f;
#pragma unroll
    for (int i = 0; i < 9; ++i) {
      int p = lane + 64 * i;
      unsigned int u0 = Lu[b0 + p], u1 = Lu[b1 + p], u2 = Lu[b2 + p];
      float a = bf2f((unsigned short)u0) + bf2f((unsigned short)u1) +
                bf2f((unsigned short)u2) + bi[i].x;
      float b = bf2f((unsigned short)(u0 >> 16)) + bf2f((unsigned short)(u1 >> 16)) +
                bf2f((unsigned short)(u2 >> 16)) + bi[i].y;
      va[2 * i] = a; va[2 * i + 1] = b;
      sum += a + b;
      sq += a * a + b * b;
    }
#pragma unroll
    for (int o = 32; o; o >>= 1) {
      sum += __shfl_xor(sum, o);
      sq += __shfl_xor(sq, o);
    }
    int orow = obase + t;
    if (w == 0) {
      float mean = sum * (1.f / OUT_DIM);
      float var = sq * (1.f / OUT_DIM) - mean * mean;
      float inv = rsqrtf(var + 1e-5f);
      unsigned short* outp = (sup ? SKb : QKb) + (size_t)orow * OUT_DIM;
#pragma unroll
      for (int i = 0; i < 9; ++i) {
        int p = lane + 64 * i;
        unsigned int lo = f2bf((va[2 * i] - mean) * inv * gg[i].x + bbv[i].x);
        unsigned int hi = f2bf((va[2 * i + 1] - mean) * inv * gg[i].y + bbv[i].y);
        *(unsigned int*)(outp + 2 * p) = lo | (hi << 16);
      }
    } else {
      unsigned short* outp = (sup ? SVb : QVb) + (size_t)orow * OUT_DIM;
#pragma unroll
      for (int i = 0; i < 9; ++i) {
        int p = lane + 64 * i;
        unsigned int lo = f2bf(va[2 * i]);
        unsigned int hi = f2bf(va[2 * i + 1]);
        *(unsigned int*)(outp + 2 * p) = lo | (hi << 16);
      }
      if (!sup && lane == 0) qnorm[orow] = sq;
    }
  }
}

// ---------------- merged: scores / G1 + Gram G2 (256x128 tiles) ----------------
// 998 blocks: 968 scores/G1 (44 rt x 11 ct x 2) + 30 G2 (5 classes x 2 rt x 3 ct)
__global__ __launch_bounds__(256, 2) void k_rowgemm(const unsigned short* __restrict__ QKb,
                                                    const unsigned short* __restrict__ SKb,
                                                    const unsigned short* __restrict__ QVb,
                                                    const unsigned short* __restrict__ SVb,
                                                    unsigned short* __restrict__ SCb,
                                                    unsigned short* __restrict__ G1b,
                                                    unsigned short* __restrict__ G2) {
  __shared__ short lds[36864];           // 3 x 24KB pipeline buffers
  int o = blockIdx.x;                    // bijective XCD swizzle for nwg=998 (q=124,r=6)
  int xcd = o & 7, idx = o >> 3;
  int L = (xcd < 6 ? xcd * 125 : 750 + (xcd - 6) * 124) + idx;
  f32x4 acc[8][4];
#pragma unroll
  for (int i = 0; i < 8; ++i)
#pragma unroll
    for (int j = 0; j < 4; ++j) acc[i][j] = (f32x4)(0.f);
  int lane = threadIdx.x & 63, wave = threadIdx.x >> 6;
  int wm = wave >> 1, wn = wave & 1, col = lane & 15, quad = lane >> 4;

  if (L < 968) {
    int g1 = L >= 484; int l = g1 ? L - 484 : L;
    int rt = l / 11, ct = l % 11;
    int row0 = rt << 8, col0 = ct << 7;
    const unsigned short* Am = g1 ? QVb : QKb;
    const unsigned short* Bm = g1 ? SVb : SKb;
    mfma_core256((const short*)Am + (size_t)row0 * OUT_DIM, OUT_DIM, min(255, QROWS - 1 - row0),
                 (const short*)Bm + (size_t)col0 * OUT_DIM, OUT_DIM, min(127, SROWS - 1 - col0),
                 OUT_DIM, lds, acc);
    unsigned short* outp = g1 ? G1b : SCb;
    const float scl = g1 ? 1.0f : 0.029462782549439483f;  // 1/sqrt(1152)
#pragma unroll
    for (int i = 0; i < 8; ++i)
#pragma unroll
      for (int r = 0; r < 4; ++r) {
        int gr = row0 + wm * 128 + i * 16 + quad * 4 + r;
        if (gr >= QROWS) continue;
#pragma unroll
        for (int j = 0; j < 4; ++j) {
          int gc = col0 + wn * 64 + j * 16 + col;
          if (gc < SROWS) {
            int c = gc / 280;
            outp[(size_t)gr * AT_STRIDE + gc + c * 8] = f2bf(acc[i][j][r] * scl);
          }
        }
      }
  } else {
    int l = L - 968;                  // 0..29: G2[c] = SV_c @ SV_c^T
    int c = l / 6, rem = l % 6;
    int rt = rem / 3, ct = rem % 3;
    int i0 = rt << 8, j0 = ct << 7;
    const short* base = (const short*)SVb + (size_t)c * 280 * OUT_DIM;
    mfma_core256(base + (size_t)i0 * OUT_DIM, OUT_DIM, 279 - i0,
                 base + (size_t)j0 * OUT_DIM, OUT_DIM, min(127, 279 - j0),
                 OUT_DIM, lds, acc);
    unsigned short* g2c = G2 + (size_t)c * KC * KC;
#pragma unroll
    for (int i = 0; i < 8; ++i)
#pragma unroll
      for (int r = 0; r < 4; ++r) {
        int gi = i0 + wm * 128 + i * 16 + quad * 4 + r;
        if (gi >= KC) continue;
#pragma unroll
        for (int j = 0; j < 4; ++j) {
          int gj = j0 + wn * 64 + j * 16 + col;
          if (gj < KC) g2c[(size_t)gi * KC + gj] = f2bf(acc[i][j][r]);
        }
      }
  }
}

// ---------------- k_attn: fused softmax + T2 + T3 (= e^T G2 e / S^2) + out atomics ----------------
// G2 (166 KB/class) is L2-resident: read B-fragments DIRECT from global (guide
// common-mistake #7 -- LDS-staging L2-fit data is pure overhead). Removes the Bs
// buffer (LDS 75 -> 38 KB => more blocks/CU) and 10 barrier drains per block.
__global__ __launch_bounds__(256) void k_attn(const unsigned short* __restrict__ SCb,
                                              const unsigned short* __restrict__ G1b,
                                              const unsigned short* __restrict__ G2,
                                              const float* __restrict__ qnorm,
                                              float* __restrict__ out) {
  __shared__ short attn[64 * ALD];     // 37,888 B
  __shared__ float T2n[64];
  __shared__ float Sarr[64];
  __shared__ float rowsum[64];
  __shared__ float val[64];
  int r0 = blockIdx.x * 64, c = blockIdx.y;
  int tid = threadIdx.x;

  // ---- phase 1: softmax numerators e = exp(s - M) -> LDS; S and T2 numerator ----
  int lr = tid >> 2, h = tid & 3;
  const unsigned short* ps = SCb + (size_t)(r0 + lr) * AT_STRIDE + c * KC;
  const unsigned short* pg = G1b + (size_t)(r0 + lr) * AT_STRIDE + c * KC;
  short8 sv[9];
  float mx = -INFINITY;
#pragma unroll
  for (int i = 0; i < 9; ++i) {
    int v = h * 9 + i;
    if (v < 35) {
      sv[i] = *(const short8*)(ps + v * 8);
#pragma unroll
      for (int j = 0; j < 8; ++j) mx = fmaxf(mx, bf2f((unsigned short)sv[i][j]));
    }
  }
  mx = fmaxf(mx, __shfl_xor(mx, 1));
  mx = fmaxf(mx, __shfl_xor(mx, 2));
  float sum = 0.f, t2 = 0.f;
#pragma unroll
  for (int i = 0; i < 9; ++i) {
    int v = h * 9 + i;
    if (v < 35) {
      short8 gv8 = *(const short8*)(pg + v * 8);
      short8 e8;
#pragma unroll
      for (int j = 0; j < 8; ++j) {
        float e = __expf(bf2f((unsigned short)sv[i][j]) - mx);
        sum += e;
        t2 += e * bf2f((unsigned short)gv8[j]);
        e8[j] = (short)f2bf(e);
      }
      *(short8*)(attn + lr * ALD + v * 8) = e8;
    } else {
      *(short8*)(attn + lr * ALD + v * 8) = (short8)0;   // zero class pad (v == 35)
    }
  }
  sum += __shfl_xor(sum, 1); sum += __shfl_xor(sum, 2);
  t2 += __shfl_xor(t2, 1); t2 += __shfl_xor(t2, 2);
  if (h == 0) { Sarr[lr] = sum; T2n[lr] = t2; }
  if (tid < 64) rowsum[tid] = 0.f;
  __syncthreads();

  // ---- phase 2: B2 = e @ G2 per 64-col slab; B read DIRECT from L2 (no staging) ----
  int lane = tid & 63, wave = tid >> 6;
  int col = lane & 15, quad = lane >> 4;
  const short* G2c = (const short*)G2 + (size_t)c * KC * KC;
  float part[4][4] = {};
  for (int j0 = 0; j0 < KC; j0 += 64) {
    int ncols = min(64, KC - j0);            // 64,64,64,64,32
    if (wave * 16 < ncols) {
      const short* brow = G2c + (size_t)(j0 + wave * 16 + col) * KC + quad * 8;
      f32x4 acc[4];
#pragma unroll
      for (int i = 0; i < 4; ++i) acc[i] = (f32x4)(0.f);
      for (int kq = 0; kq < 9; ++kq) {
        short8 bf = *(const short8*)(brow + kq * 32);
#pragma unroll
        for (int i = 0; i < 4; ++i) {
          short8 af = *(const short8*)(attn + (i * 16 + col) * ALD + kq * 32 + quad * 8);
          acc[i] = __builtin_amdgcn_mfma_f32_16x16x32_bf16(af, bf, acc[i], 0, 0, 0);
        }
      }
      int gcol = j0 + wave * 16 + col;
#pragma unroll
      for (int i = 0; i < 4; ++i)
#pragma unroll
        for (int r = 0; r < 4; ++r)
          part[i][r] += bf2f((unsigned short)attn[(i * 16 + quad * 4 + r) * ALD + gcol]) *
                        acc[i][r];
    }
  }
  // reduce rowdot across the wave's 16 cols, then across waves via LDS atomics
#pragma unroll
  for (int i = 0; i < 4; ++i)
#pragma unroll
    for (int r = 0; r < 4; ++r) {
      float s = part[i][r];
      s += __shfl_xor(s, 1); s += __shfl_xor(s, 2);
      s += __shfl_xor(s, 4); s += __shfl_xor(s, 8);
      if (col == 0) atomicAdd(&rowsum[i * 16 + quad * 4 + r], s);
    }
  __syncthreads();

  // ---- phase 3: per-row distance, per-query reduce, one atomic per (q, c) ----
  if (tid < 64) {
    float S = Sarr[tid], invS = 1.f / S;
    val[tid] = qnorm[r0 + tid] - 2.f * T2n[tid] * invS + rowsum[tid] * invS * invS;
  }
  __syncthreads();
  if (tid < 3) {
    int q = r0 / NTUP + tid;
    int lo = max(q * NTUP, r0), hi = min(q * NTUP + NTUP, r0 + 64);
    if (lo < hi && q < NQ) {
      float s = 0.f;
      for (int r = lo; r < hi; ++r) s += val[r - r0];
      atomicAdd(&out[q * WAY + c], -s * (1.f / NTUP));
    }
  }
}

// ---------------- launch ----------------
extern "C" void kernel_launch(void* const* d_in, const int* in_sizes, int n_in,
                              void* d_out, int out_size, void* d_ws, size_t ws_size,
                              hipStream_t stream) {
  const float* support = (const float*)d_in[0];
  const int* labels = (const int*)d_in[1];
  const float* queries = (const float*)d_in[2];
  const float* Wk = (const float*)d_in[3];
  const float* bk = (const float*)d_in[4];
  const float* Wv = (const float*)d_in[5];
  const float* bv = (const float*)d_in[6];
  const float* ln_g = (const float*)d_in[7];
  const float* ln_b = (const float*)d_in[8];
  float* out = (float*)d_out;
  char* w8 = (char*)d_ws;

  unsigned short* APb = (unsigned short*)(w8 + APB_OFF);
  unsigned short* WT = (unsigned short*)(w8 + WT_OFF);
  unsigned short* Pb = (unsigned short*)(w8 + PB_OFF);
  unsigned short* QKb = (unsigned short*)(w8 + QKB_OFF);
  unsigned short* SKb = (unsigned short*)(w8 + SKB_OFF);
  unsigned short* QVb = (unsigned short*)(w8 + QVB_OFF);
  unsigned short* SVb = (unsigned short*)(w8 + SVB_OFF);
  unsigned short* G2 = (unsigned short*)(w8 + G2_OFF);
  unsigned short* SCb = (unsigned short*)(w8 + SCB_OFF);
  unsigned short* G1b = (unsigned short*)(w8 + G1B_OFF);
  float* QNORM = (float*)(w8 + QNORM_OFF);
  int* RANK = (int*)(w8 + RANK_OFF);

  k_pre<<<dim3(NFRAMES + 13824 + 1), dim3(256), 0, stream>>>(support, queries, Wk, Wv,
                                                             labels, APb, WT, RANK, out);
  k_gemm1<<<dim3(432), dim3(256), 0, stream>>>(APb, WT, Pb);
  k_combine<<<dim3(225, 2, 2), dim3(256), 0, stream>>>(Pb, bk, bv, ln_g, ln_b, RANK,
                                                       SKb, QKb, SVb, QVb, QNORM);
  k_rowgemm<<<dim3(998), dim3(256), 0, stream>>>(QKb, SKb, QVb, SVb, SCb, G1b, G2);
  k_attn<<<dim3(175, 5), dim3(256), 0, stream>>>(SCb, G1b, G2, QNORM, out);
}

// Round 8
// 341.979 us; speedup vs baseline: 3.6065x; 1.0371x over previous
//
#include <hip/hip_runtime.h>
#include <math.h>

// ---------------- problem constants ----------------
#define SEQ_LEN 8
#define IN_DIM 2048
#define OUT_DIM 1152
#define NTUP 56
#define NSUP 25
#define NQ 200
#define WAY 5
#define SFRAMES 200
#define NFRAMES 1800
#define SROWS 1400
#define QROWS 11200
#define AT_STRIDE 1440   // bf16 scores/G1 row stride: 5 classes * 288
#define KC 288           // per-class padded K (280 valid + 8 zeros)
#define ALD 296          // attn LDS row stride (shorts)

typedef __attribute__((ext_vector_type(8))) short short8;
typedef __attribute__((ext_vector_type(4))) float f32x4;

__device__ __constant__ int TUP[NTUP][3] = {
{0,1,2},{0,1,3},{0,1,4},{0,1,5},{0,1,6},{0,1,7},
{0,2,3},{0,2,4},{0,2,5},{0,2,6},{0,2,7},
{0,3,4},{0,3,5},{0,3,6},{0,3,7},
{0,4,5},{0,4,6},{0,4,7},
{0,5,6},{0,5,7},
{0,6,7},
{1,2,3},{1,2,4},{1,2,5},{1,2,6},{1,2,7},
{1,3,4},{1,3,5},{1,3,6},{1,3,7},
{1,4,5},{1,4,6},{1,4,7},
{1,5,6},{1,5,7},
{1,6,7},
{2,3,4},{2,3,5},{2,3,6},{2,3,7},
{2,4,5},{2,4,6},{2,4,7},
{2,5,6},{2,5,7},
{2,6,7},
{3,4,5},{3,4,6},{3,4,7},
{3,5,6},{3,5,7},
{3,6,7},
{4,5,6},{4,5,7},
{4,6,7},
{5,6,7}};

// ---------------- bf16 helpers ----------------
__device__ __forceinline__ unsigned short f2bf(float x) {
  union { float f; unsigned int u; } v; v.f = x;
  unsigned int r = v.u + 0x7fffu + ((v.u >> 16) & 1u);
  return (unsigned short)(r >> 16);
}
__device__ __forceinline__ float bf2f(unsigned short s) {
  union { float f; unsigned int u; } v; v.u = ((unsigned int)s) << 16;
  return v.f;
}

// async 16B global -> LDS (dest = wave-uniform base + lane*16; tid-contiguous ok)
__device__ __forceinline__ void gll16(const void* g, void* l) {
  __builtin_amdgcn_global_load_lds(
      (const __attribute__((address_space(1))) unsigned int*)g,
      (__attribute__((address_space(3))) unsigned int*)l, 16, 0, 0);
}

// counted vmcnt wait (T4)
#define VMCNT(N) asm volatile("s_waitcnt vmcnt(" #N ")" ::: "memory")

// raw workgroup barrier WITHOUT the compiler's vmcnt(0) drain
__device__ __forceinline__ void pbar() {
  asm volatile("" ::: "memory");
  __builtin_amdgcn_s_barrier();
  asm volatile("" ::: "memory");
}

// ---------------- workspace byte offsets ----------------
#define APB_OFF   0UL                     // bf16 [1800][2048]
#define WT_OFF    7372800UL               // bf16 [6912][2048]
#define PB_OFF    35684352UL              // bf16 [1800][6912]
#define QKB_OFF   60567552UL              // bf16 [11200][1152]
#define SKB_OFF   86372352UL              // bf16 [1400][1152] class-sorted
#define QVB_OFF   89597952UL              // bf16 [11200][1152]
#define SVB_OFF   115402752UL             // bf16 [1400][1152] class-sorted
#define G2_OFF    118628352UL             // bf16 [5][288][288] Gram
#define SCB_OFF   119457792UL             // bf16 [11200][1440] class-padded
#define G1B_OFF   151713792UL             // bf16 [11200][1440] class-padded
#define QNORM_OFF 183969792UL             // f32  [11200]
#define RANK_OFF  184014592UL             // i32  [25]

// ---------------- k_pre: fused (X+PE)->bf16, weight transpose, rank, out-zero ----------------
__global__ __launch_bounds__(256) void k_pre(const float* __restrict__ S,
                                             const float* __restrict__ Q,
                                             const float* __restrict__ Wk,
                                             const float* __restrict__ Wv,
                                             const int* __restrict__ labels,
                                             unsigned short* __restrict__ APb,
                                             unsigned short* __restrict__ WT,
                                             int* __restrict__ rank,
                                             float* __restrict__ outz) {
  __shared__ float t[32][33];
  int b = blockIdx.x, tid = threadIdx.x;
  if (b < NFRAMES) {
    int frame = b;
    int e8 = tid * 8;
    int pos = frame & 7;
    const float c0 = -logf(10000.0f) / (float)IN_DIM;
    float pe[8];
#pragma unroll
    for (int p = 0; p < 4; ++p) {
      float dt = expf((float)(e8 + 2 * p) * c0);
      float arg = (float)pos * dt;
      pe[2 * p] = sinf(arg) * 0.1f;
      pe[2 * p + 1] = cosf(arg) * 0.1f;
    }
    const float* src = (frame < SFRAMES) ? (S + (size_t)frame * IN_DIM + e8)
                                         : (Q + (size_t)(frame - SFRAMES) * IN_DIM + e8);
    float4 x0 = ((const float4*)src)[0], x1 = ((const float4*)src)[1];
    short8 o;
    o[0] = (short)f2bf(x0.x + pe[0]); o[1] = (short)f2bf(x0.y + pe[1]);
    o[2] = (short)f2bf(x0.z + pe[2]); o[3] = (short)f2bf(x0.w + pe[3]);
    o[4] = (short)f2bf(x1.x + pe[4]); o[5] = (short)f2bf(x1.y + pe[5]);
    o[6] = (short)f2bf(x1.z + pe[6]); o[7] = (short)f2bf(x1.w + pe[7]);
    *(short8*)(APb + (size_t)frame * IN_DIM + e8) = o;
  } else if (b < NFRAMES + 13824) {
    int z = b - NFRAMES;                  // 64 k-tiles x 36 d-tiles x 6 (w,j)
    int bz = z / (64 * 36); int rem = z % (64 * 36);
    int by = rem / 64, bx = rem % 64;
    int w = bz / 3, j = bz % 3;
    const float* W = w ? Wv : Wk;
    int k0 = bx * 32, d0 = by * 32;
    int tx = tid & 31, ty = tid >> 5;
#pragma unroll
    for (int i = 0; i < 4; ++i) {
      int k = k0 + ty + i * 8;
      t[ty + i * 8][tx] = W[(size_t)(j * IN_DIM + k) * OUT_DIM + d0 + tx];
    }
    __syncthreads();
    int colbase = w * 3456 + j * 1152 + d0;
#pragma unroll
    for (int i = 0; i < 4; ++i) {
      int d = ty + i * 8;
      WT[(size_t)(colbase + d) * IN_DIM + k0 + tx] = f2bf(t[tx][d]);
    }
  } else {
    for (int i = tid; i < NQ * WAY; i += 256) outz[i] = 0.f;
    if (tid == 0) {
      for (int s = 0; s < NSUP; ++s) {
        int r = 0;
        for (int s2 = 0; s2 < NSUP; ++s2)
          r += (labels[s2] < labels[s]) || (labels[s2] == labels[s] && s2 < s);
        rank[s] = r;
      }
    }
  }
}

// ---------------- MFMA GEMM core: BM=256 x BN=128, BK=32, 256 thr / 4 waves ----------------
// Round-4 proven config (best measured: k_rowgemm 96 us, total 345.7). Chunk-XOR
// layout (0 bank conflicts), depth-2 prefetch over 3 x 24KB LDS buffers, single
// barrier per iter, counted vmcnt(6). REGISTER BUDGET (round-5 lesson): needs
// ~230 unified VGPR/AGPR; __launch_bounds__(256,2) => 256-reg cap, no spill.
// (256,3) spilled acc -> 1.3 GB scratch traffic. Round-6 lesson: B through
// registers/global instead of LDS is SLOWER (L2 latency in MFMA dep chain).
__device__ __forceinline__ void mfma_core256(const short* __restrict__ A, int lda, int maxA,
                                             const short* __restrict__ B, int ldb, int maxB,
                                             int K, short* lds, f32x4 (&acc)[8][4]) {
  int tid = threadIdx.x;
  int lane = tid & 63, wave = tid >> 6;
  int wm = wave >> 1, wn = wave & 1;
  int col = lane & 15, quad = lane >> 4;
  int kq8 = (quad ^ ((col >> 1) & 3)) * 8;     // read-side swizzled k-chunk (shorts)

  // staging: A = 1024 slots (256 rows x 4 chunks), B = 512 slots; 6 gll16/thread
  int rt_ = tid >> 2;                          // slot row base 0..63
  int qo = ((tid & 3) ^ ((tid >> 3) & 3)) * 8; // inverse-swizzled source chunk
  const short* a0p = A + (size_t)min(rt_,       maxA) * lda + qo;
  const short* a1p = A + (size_t)min(rt_ + 64,  maxA) * lda + qo;
  const short* a2p = A + (size_t)min(rt_ + 128, maxA) * lda + qo;
  const short* a3p = A + (size_t)min(rt_ + 192, maxA) * lda + qo;
  const short* b0p = B + (size_t)min(rt_,       maxB) * ldb + qo;
  const short* b1p = B + (size_t)min(rt_ + 64,  maxB) * ldb + qo;
  const int nt = K >> 5;

#define STAGE(t, cb)                                 \
  do {                                               \
    short* buf_ = lds + (cb);                        \
    int k0_ = (t) << 5;                              \
    gll16(a0p + k0_, buf_ + (size_t)tid * 8);        \
    gll16(a1p + k0_, buf_ + (size_t)(tid + 256) * 8);\
    gll16(a2p + k0_, buf_ + (size_t)(tid + 512) * 8);\
    gll16(a3p + k0_, buf_ + (size_t)(tid + 768) * 8);\
    gll16(b0p + k0_, buf_ + 8192 + (size_t)tid * 8); \
    gll16(b1p + k0_, buf_ + 8192 + (size_t)(tid + 256) * 8);\
  } while (0)

  // prologue: tiles 0,1 in flight; confirm tile 0 only (tile 1's 6 ride on)
  STAGE(0, 0);
  STAGE(1, 12288);
  VMCNT(6);
  pbar();
  int c0 = 0, c1 = 12288, c2 = 24576;          // rotating buffer offsets (shorts)
  for (int t = 0; t < nt; ++t) {
    if (t + 2 < nt) STAGE(t + 2, c2);          // depth-2 prefetch into stale buffer
    const short* As = lds + c0;
    const short* Bs = As + 8192;
    short8 af[8], bf[4];
#pragma unroll
    for (int i = 0; i < 8; ++i)
      af[i] = *(const short8*)(As + (wm * 128 + i * 16 + col) * 32 + kq8);
#pragma unroll
    for (int j = 0; j < 4; ++j)
      bf[j] = *(const short8*)(Bs + (wn * 64 + j * 16 + col) * 32 + kq8);
    __builtin_amdgcn_s_setprio(1);
#pragma unroll
    for (int i = 0; i < 8; ++i)
#pragma unroll
      for (int j = 0; j < 4; ++j)
        acc[i][j] = __builtin_amdgcn_mfma_f32_16x16x32_bf16(af[i], bf[j], acc[i][j], 0, 0, 0);
    __builtin_amdgcn_s_setprio(0);
    if (t + 2 < nt)      VMCNT(6);             // tile t+1 landed; t+2 stays in flight
    else if (t + 1 < nt) VMCNT(0);             // epilogue drain (once)
    pbar();                                    // single barrier per iter
    int tmp = c0; c0 = c1; c1 = c2; c2 = tmp;
  }
#undef STAGE
}

// ---------------- GEMM1: Pb[1800][6912] = APb @ WT^T (256x128 tiles) ----------------
__global__ __launch_bounds__(256, 2) void k_gemm1(const unsigned short* __restrict__ APb,
                                                  const unsigned short* __restrict__ WT,
                                                  unsigned short* __restrict__ Pb) {
  __shared__ short lds[36864];           // 3 x 24KB pipeline buffers
  int o = blockIdx.x;                    // 432 blocks; XCD swizzle (432 % 8 == 0)
  int L = (o & 7) * 54 + (o >> 3);
  int rt = L / 54, ct = L % 54;
  int row0 = rt << 8, col0 = ct << 7;
  f32x4 acc[8][4];
#pragma unroll
  for (int i = 0; i < 8; ++i)
#pragma unroll
    for (int j = 0; j < 4; ++j) acc[i][j] = (f32x4)(0.f);
  mfma_core256((const short*)APb + (size_t)row0 * IN_DIM, IN_DIM, min(255, NFRAMES - 1 - row0),
               (const short*)WT + (size_t)col0 * IN_DIM, IN_DIM, 127,
               IN_DIM, lds, acc);
  int lane = threadIdx.x & 63, wave = threadIdx.x >> 6;
  int wm = wave >> 1, wn = wave & 1, col = lane & 15, quad = lane >> 4;
#pragma unroll
  for (int i = 0; i < 8; ++i)
#pragma unroll
    for (int r = 0; r < 4; ++r) {
      int gr = row0 + wm * 128 + i * 16 + quad * 4 + r;
      if (gr >= NFRAMES) continue;
#pragma unroll
      for (int j = 0; j < 4; ++j)
        Pb[(size_t)gr * 6912 + col0 + wn * 64 + j * 16 + col] = f2bf(acc[i][j][r]);
    }
}

// ---------------- combine (clip-LDS): one block per (clip, k/v) ----------------
__global__ __launch_bounds__(256) void k_combine(const unsigned short* __restrict__ Pb,
                                                 const float* __restrict__ bk,
                                                 const float* __restrict__ bv,
                                                 const float* __restrict__ g,
                                                 const float* __restrict__ bb,
                                                 const int* __restrict__ rank,
                                                 unsigned short* __restrict__ SKb,
                                                 unsigned short* __restrict__ QKb,
                                                 unsigned short* __restrict__ SVb,
                                                 unsigned short* __restrict__ QVb,
                                                 float* __restrict__ qnorm) {
  __shared__ short L[8 * 3456];
  int n = blockIdx.x, w = blockIdx.y;
  int tid = threadIdx.x;
  bool sup = n < NSUP;
  int fbase = sup ? n * SEQ_LEN : SFRAMES + (n - NSUP) * SEQ_LEN;
  for (int i = 0; i < 14; ++i) {
    int idx = tid + 256 * i;          // vec8 index < 3456
    if (idx < 3456) {
      int fr = idx / 432, off = (idx - fr * 432) * 8;
      *(short8*)(L + fr * 3456 + off) =
          *(const short8*)(Pb + (size_t)(fbase + fr) * 6912 + w * 3456 + off);
    }
  }
  __syncthreads();
  int wave = tid >> 6, lane = tid & 63;
  const float* bias = w ? bv : bk;
  float2 bi[9], gg[9], bbv[9];
#pragma unroll
  for (int i = 0; i < 9; ++i) {
    int p = lane + 64 * i;
    bi[i] = *(const float2*)(bias + 2 * p);
    if (w == 0) {
      gg[i] = *(const float2*)(g + 2 * p);
      bbv[i] = *(const float2*)(bb + 2 * p);
    }
  }
  int obase = sup ? rank[n] * NTUP : (n - NSUP) * NTUP;
  const unsigned int* Lu = (const unsigned int*)L;
  for (int t = wave; t < NTUP; t += 4) {
    int b0 = (TUP[t][0] * 3456) >> 1;
    int b1 = (TUP[t][1] * 3456 + 1152) >> 1;
    int b2 = (TUP[t][2] * 3456 + 2304) >> 1;
    float va[18];
    float sum = 0.f, sq = 0.f;
#pragma unroll
    for (int i = 0; i < 9; ++i) {
      int p = lane + 64 * i;
      unsigned int u0 = Lu[b0 + p], u1 = Lu[b1 + p], u2 = Lu[b2 + p];
      float a = bf2f((unsigned short)u0) + bf2f((unsigned short)u1) +
                bf2f((unsigned short)u2) + bi[i].x;
      float b = bf2f((unsigned short)(u0 >> 16)) + bf2f((unsigned short)(u1 >> 16)) +
                bf2f((unsigned short)(u2 >> 16)) + bi[i].y;
      va[2 * i] = a; va[2 * i + 1] = b;
      sum += a + b;
      sq += a * a + b * b;
    }
#pragma unroll
    for (int o = 32; o; o >>= 1) {
      sum += __shfl_xor(sum, o);
      sq += __shfl_xor(sq, o);
    }
    int orow = obase + t;
    if (w == 0) {
      float mean = sum * (1.f / OUT_DIM);
      float var = sq * (1.f / OUT_DIM) - mean * mean;
      float inv = rsqrtf(var + 1e-5f);
      unsigned short* outp = (sup ? SKb : QKb) + (size_t)orow * OUT_DIM;
#pragma unroll
      for (int i = 0; i < 9; ++i) {
        int p = lane + 64 * i;
        unsigned int lo = f2bf((va[2 * i] - mean) * inv * gg[i].x + bbv[i].x);
        unsigned int hi = f2bf((va[2 * i + 1] - mean) * inv * gg[i].y + bbv[i].y);
        *(unsigned int*)(outp + 2 * p) = lo | (hi << 16);
      }
    } else {
      unsigned short* outp = (sup ? SVb : QVb) + (size_t)orow * OUT_DIM;
#pragma unroll
      for (int i = 0; i < 9; ++i) {
        int p = lane + 64 * i;
        unsigned int lo = f2bf(va[2 * i]);
        unsigned int hi = f2bf(va[2 * i + 1]);
        *(unsigned int*)(outp + 2 * p) = lo | (hi << 16);
      }
      if (!sup && lane == 0) qnorm[orow] = sq;
    }
  }
}

// ---------------- merged: scores / G1 + Gram G2 (256x128 tiles) ----------------
// 998 blocks: 968 scores/G1 (44 rt x 11 ct x 2) + 30 G2 (5 classes x 2 rt x 3 ct)
__global__ __launch_bounds__(256, 2) void k_rowgemm(const unsigned short* __restrict__ QKb,
                                                    const unsigned short* __restrict__ SKb,
                                                    const unsigned short* __restrict__ QVb,
                                                    const unsigned short* __restrict__ SVb,
                                                    unsigned short* __restrict__ SCb,
                                                    unsigned short* __restrict__ G1b,
                                                    unsigned short* __restrict__ G2) {
  __shared__ short lds[36864];           // 3 x 24KB pipeline buffers
  int o = blockIdx.x;                    // bijective XCD swizzle for nwg=998 (q=124,r=6)
  int xcd = o & 7, idx = o >> 3;
  int L = (xcd < 6 ? xcd * 125 : 750 + (xcd - 6) * 124) + idx;
  f32x4 acc[8][4];
#pragma unroll
  for (int i = 0; i < 8; ++i)
#pragma unroll
    for (int j = 0; j < 4; ++j) acc[i][j] = (f32x4)(0.f);
  int lane = threadIdx.x & 63, wave = threadIdx.x >> 6;
  int wm = wave >> 1, wn = wave & 1, col = lane & 15, quad = lane >> 4;

  if (L < 968) {
    int g1 = L >= 484; int l = g1 ? L - 484 : L;
    int rt = l / 11, ct = l % 11;
    int row0 = rt << 8, col0 = ct << 7;
    const unsigned short* Am = g1 ? QVb : QKb;
    const unsigned short* Bm = g1 ? SVb : SKb;
    mfma_core256((const short*)Am + (size_t)row0 * OUT_DIM, OUT_DIM, min(255, QROWS - 1 - row0),
                 (const short*)Bm + (size_t)col0 * OUT_DIM, OUT_DIM, min(127, SROWS - 1 - col0),
                 OUT_DIM, lds, acc);
    unsigned short* outp = g1 ? G1b : SCb;
    const float scl = g1 ? 1.0f : 0.029462782549439483f;  // 1/sqrt(1152)
#pragma unroll
    for (int i = 0; i < 8; ++i)
#pragma unroll
      for (int r = 0; r < 4; ++r) {
        int gr = row0 + wm * 128 + i * 16 + quad * 4 + r;
        if (gr >= QROWS) continue;
#pragma unroll
        for (int j = 0; j < 4; ++j) {
          int gc = col0 + wn * 64 + j * 16 + col;
          if (gc < SROWS) {
            int c = gc / 280;
            outp[(size_t)gr * AT_STRIDE + gc + c * 8] = f2bf(acc[i][j][r] * scl);
          }
        }
      }
  } else {
    int l = L - 968;                  // 0..29: G2[c] = SV_c @ SV_c^T
    int c = l / 6, rem = l % 6;
    int rt = rem / 3, ct = rem % 3;
    int i0 = rt << 8, j0 = ct << 7;
    const short* base = (const short*)SVb + (size_t)c * 280 * OUT_DIM;
    mfma_core256(base + (size_t)i0 * OUT_DIM, OUT_DIM, 279 - i0,
                 base + (size_t)j0 * OUT_DIM, OUT_DIM, min(127, 279 - j0),
                 OUT_DIM, lds, acc);
    unsigned short* g2c = G2 + (size_t)c * KC * KC;
#pragma unroll
    for (int i = 0; i < 8; ++i)
#pragma unroll
      for (int r = 0; r < 4; ++r) {
        int gi = i0 + wm * 128 + i * 16 + quad * 4 + r;
        if (gi >= KC) continue;
#pragma unroll
        for (int j = 0; j < 4; ++j) {
          int gj = j0 + wn * 64 + j * 16 + col;
          if (gj < KC) g2c[(size_t)gi * KC + gj] = f2bf(acc[i][j][r]);
        }
      }
  }
}

// ---------------- k_attn: fused softmax + T2 + T3 (= e^T G2 e / S^2) + out atomics ----------------
// G2 (166 KB/class) is L2-resident: read B-fragments DIRECT from global (guide
// common-mistake #7 -- LDS-staging L2-fit data is pure overhead). Removes the Bs
// buffer (LDS 75 -> 38 KB => more blocks/CU) and 10 barrier drains per block.
// Confirmed in round 7: k_attn+combine changes netted ~-21 us vs round 4.
__global__ __launch_bounds__(256) void k_attn(const unsigned short* __restrict__ SCb,
                                              const unsigned short* __restrict__ G1b,
                                              const unsigned short* __restrict__ G2,
                                              const float* __restrict__ qnorm,
                                              float* __restrict__ out) {
  __shared__ short attn[64 * ALD];     // 37,888 B
  __shared__ float T2n[64];
  __shared__ float Sarr[64];
  __shared__ float rowsum[64];
  __shared__ float val[64];
  int r0 = blockIdx.x * 64, c = blockIdx.y;
  int tid = threadIdx.x;

  // ---- phase 1: softmax numerators e = exp(s - M) -> LDS; S and T2 numerator ----
  int lr = tid >> 2, h = tid & 3;
  const unsigned short* ps = SCb + (size_t)(r0 + lr) * AT_STRIDE + c * KC;
  const unsigned short* pg = G1b + (size_t)(r0 + lr) * AT_STRIDE + c * KC;
  short8 sv[9];
  float mx = -INFINITY;
#pragma unroll
  for (int i = 0; i < 9; ++i) {
    int v = h * 9 + i;
    if (v < 35) {
      sv[i] = *(const short8*)(ps + v * 8);
#pragma unroll
      for (int j = 0; j < 8; ++j) mx = fmaxf(mx, bf2f((unsigned short)sv[i][j]));
    }
  }
  mx = fmaxf(mx, __shfl_xor(mx, 1));
  mx = fmaxf(mx, __shfl_xor(mx, 2));
  float sum = 0.f, t2 = 0.f;
#pragma unroll
  for (int i = 0; i < 9; ++i) {
    int v = h * 9 + i;
    if (v < 35) {
      short8 gv8 = *(const short8*)(pg + v * 8);
      short8 e8;
#pragma unroll
      for (int j = 0; j < 8; ++j) {
        float e = __expf(bf2f((unsigned short)sv[i][j]) - mx);
        sum += e;
        t2 += e * bf2f((unsigned short)gv8[j]);
        e8[j] = (short)f2bf(e);
      }
      *(short8*)(attn + lr * ALD + v * 8) = e8;
    } else {
      *(short8*)(attn + lr * ALD + v * 8) = (short8)0;   // zero class pad (v == 35)
    }
  }
  sum += __shfl_xor(sum, 1); sum += __shfl_xor(sum, 2);
  t2 += __shfl_xor(t2, 1); t2 += __shfl_xor(t2, 2);
  if (h == 0) { Sarr[lr] = sum; T2n[lr] = t2; }
  if (tid < 64) rowsum[tid] = 0.f;
  __syncthreads();

  // ---- phase 2: B2 = e @ G2 per 64-col slab; B read DIRECT from L2 (no staging) ----
  int lane = tid & 63, wave = tid >> 6;
  int col = lane & 15, quad = lane >> 4;
  const short* G2c = (const short*)G2 + (size_t)c * KC * KC;
  float part[4][4] = {};
  for (int j0 = 0; j0 < KC; j0 += 64) {
    int ncols = min(64, KC - j0);            // 64,64,64,64,32
    if (wave * 16 < ncols) {
      const short* brow = G2c + (size_t)(j0 + wave * 16 + col) * KC + quad * 8;
      f32x4 acc[4];
#pragma unroll
      for (int i = 0; i < 4; ++i) acc[i] = (f32x4)(0.f);
      for (int kq = 0; kq < 9; ++kq) {
        short8 bf = *(const short8*)(brow + kq * 32);
#pragma unroll
        for (int i = 0; i < 4; ++i) {
          short8 af = *(const short8*)(attn + (i * 16 + col) * ALD + kq * 32 + quad * 8);
          acc[i] = __builtin_amdgcn_mfma_f32_16x16x32_bf16(af, bf, acc[i], 0, 0, 0);
        }
      }
      int gcol = j0 + wave * 16 + col;
#pragma unroll
      for (int i = 0; i < 4; ++i)
#pragma unroll
        for (int r = 0; r < 4; ++r)
          part[i][r] += bf2f((unsigned short)attn[(i * 16 + quad * 4 + r) * ALD + gcol]) *
                        acc[i][r];
    }
  }
  // reduce rowdot across the wave's 16 cols, then across waves via LDS atomics
#pragma unroll
  for (int i = 0; i < 4; ++i)
#pragma unroll
    for (int r = 0; r < 4; ++r) {
      float s = part[i][r];
      s += __shfl_xor(s, 1); s += __shfl_xor(s, 2);
      s += __shfl_xor(s, 4); s += __shfl_xor(s, 8);
      if (col == 0) atomicAdd(&rowsum[i * 16 + quad * 4 + r], s);
    }
  __syncthreads();

  // ---- phase 3: per-row distance, per-query reduce, one atomic per (q, c) ----
  if (tid < 64) {
    float S = Sarr[tid], invS = 1.f / S;
    val[tid] = qnorm[r0 + tid] - 2.f * T2n[tid] * invS + rowsum[tid] * invS * invS;
  }
  __syncthreads();
  if (tid < 3) {
    int q = r0 / NTUP + tid;
    int lo = max(q * NTUP, r0), hi = min(q * NTUP + NTUP, r0 + 64);
    if (lo < hi && q < NQ) {
      float s = 0.f;
      for (int r = lo; r < hi; ++r) s += val[r - r0];
      atomicAdd(&out[q * WAY + c], -s * (1.f / NTUP));
    }
  }
}

// ---------------- launch ----------------
extern "C" void kernel_launch(void* const* d_in, const int* in_sizes, int n_in,
                              void* d_out, int out_size, void* d_ws, size_t ws_size,
                              hipStream_t stream) {
  const float* support = (const float*)d_in[0];
  const int* labels = (const int*)d_in[1];
  const float* queries = (const float*)d_in[2];
  const float* Wk = (const float*)d_in[3];
  const float* bk = (const float*)d_in[4];
  const float* Wv = (const float*)d_in[5];
  const float* bv = (const float*)d_in[6];
  const float* ln_g = (const float*)d_in[7];
  const float* ln_b = (const float*)d_in[8];
  float* out = (float*)d_out;
  char* w8 = (char*)d_ws;

  unsigned short* APb = (unsigned short*)(w8 + APB_OFF);
  unsigned short* WT = (unsigned short*)(w8 + WT_OFF);
  unsigned short* Pb = (unsigned short*)(w8 + PB_OFF);
  unsigned short* QKb = (unsigned short*)(w8 + QKB_OFF);
  unsigned short* SKb = (unsigned short*)(w8 + SKB_OFF);
  unsigned short* QVb = (unsigned short*)(w8 + QVB_OFF);
  unsigned short* SVb = (unsigned short*)(w8 + SVB_OFF);
  unsigned short* G2 = (unsigned short*)(w8 + G2_OFF);
  unsigned short* SCb = (unsigned short*)(w8 + SCB_OFF);
  unsigned short* G1b = (unsigned short*)(w8 + G1B_OFF);
  float* QNORM = (float*)(w8 + QNORM_OFF);
  int* RANK = (int*)(w8 + RANK_OFF);

  k_pre<<<dim3(NFRAMES + 13824 + 1), dim3(256), 0, stream>>>(support, queries, Wk, Wv,
                                                             labels, APb, WT, RANK, out);
  k_gemm1<<<dim3(432), dim3(256), 0, stream>>>(APb, WT, Pb);
  k_combine<<<dim3(225, 2), dim3(256), 0, stream>>>(Pb, bk, bv, ln_g, ln_b, RANK,
                                                    SKb, QKb, SVb, QVb, QNORM);
  k_rowgemm<<<dim3(998), dim3(256), 0, stream>>>(QKb, SKb, QVb, SVb, SCb, G1b, G2);
  k_attn<<<dim3(175, 5), dim3(256), 0, stream>>>(SCb, G1b, G2, QNORM, out);
}